// Round 1
// baseline (3061.400 us; speedup 1.0000x reference)
//
#include <hip/hip_runtime.h>

#define N_NODES_C 50000
#define N_EDGES_C 500000
#define EDGE_DIM_C 16
#define DIM_C 128
#define N_LAYERS_C 3
#define N_GRAPHS_C 512
#define N_CLASSES_C 10
#define BN_EPS_C 1e-5f

#define ETILE 64
#define TPAD 132   // padded LDS row stride (128+4) -> spreads t1 reads across banks

// -------------------------------------------------------------------------
// Fused edge kernel: edge-encoder MLP (16->128->128) + BN + message
// relu(x[src]+e) + atomic scatter-add into agg[dst].
// Block = 512 threads, 64-edge tiles, weights staged in LDS once per block.
// Thread (fg = tid&15, eg = tid>>4) owns 2 edges x 8 features
// (features fg*4..fg*4+3 and 64+fg*4..64+fg*4+3).
// -------------------------------------------------------------------------
__global__ __launch_bounds__(512)
void edge_kernel(const float* __restrict__ edge_attr,
                 const float* __restrict__ x,
                 const int* __restrict__ src,
                 const int* __restrict__ dst,
                 const float* __restrict__ W1,
                 const float* __restrict__ b1,
                 const float* __restrict__ W2,
                 const float* __restrict__ b2,
                 const float* __restrict__ bng,
                 const float* __restrict__ bnb,
                 const float* __restrict__ bnrm,
                 const float* __restrict__ bnrv,
                 float* __restrict__ agg)
{
    __shared__ float W1s[EDGE_DIM_C][DIM_C];   // 8 KB
    __shared__ float W2s[DIM_C][DIM_C];        // 64 KB
    __shared__ float t1s[ETILE][TPAD];         // 33.8 KB
    __shared__ float eas[ETILE][EDGE_DIM_C];   // 4 KB
    __shared__ float b1s[DIM_C], b2s[DIM_C], bscs[DIM_C], bshs[DIM_C];
    __shared__ int   srcs[ETILE], dsts[ETILE];

    const int tid = threadIdx.x;

    // ---- stage weights once per block ----
    for (int i = tid; i < EDGE_DIM_C * DIM_C / 4; i += 512)
        ((float4*)W1s)[i] = ((const float4*)W1)[i];
    for (int i = tid; i < DIM_C * DIM_C / 4; i += 512)
        ((float4*)W2s)[i] = ((const float4*)W2)[i];
    if (tid < DIM_C) {
        b1s[tid] = b1[tid];
        b2s[tid] = b2[tid];
        float sc = bng[tid] * rsqrtf(bnrv[tid] + BN_EPS_C);
        bscs[tid] = sc;
        bshs[tid] = bnb[tid] - bnrm[tid] * sc;
    }
    __syncthreads();

    const int fg  = tid & 15;
    const int eg  = tid >> 4;
    const int e0  = eg * 2;
    const int flo = fg * 4;
    const int fhi = flo + 64;

    const int ntiles = (N_EDGES_C + ETILE - 1) / ETILE;
    for (int t = blockIdx.x; t < ntiles; t += gridDim.x) {
        const int base  = t * ETILE;
        const int count = min(ETILE, N_EDGES_C - base);

        // ---- load edge_attr tile + indices ----
        for (int i = tid; i < count * EDGE_DIM_C; i += 512)
            ((float*)eas)[i] = edge_attr[base * EDGE_DIM_C + i];
        if (tid < count) srcs[tid] = src[base + tid];
        else if (tid >= 64 && tid < 64 + count) dsts[tid - 64] = dst[base + tid - 64];
        __syncthreads();

        // ---- stage1: t1 = relu(ea @ W1 + b1) ----
        for (int idx = tid; idx < ETILE * DIM_C; idx += 512) {
            int e = idx >> 7;
            if (e < count) {
                int f = idx & 127;
                float a = b1s[f];
                #pragma unroll
                for (int k = 0; k < EDGE_DIM_C; ++k)
                    a += eas[e][k] * W1s[k][f];
                t1s[e][f] = fmaxf(a, 0.f);
            }
        }
        __syncthreads();

        // ---- stage2: t2 = t1 @ W2 + b2, register-tiled ----
        float acc[2][8];
        #pragma unroll
        for (int j = 0; j < 4; ++j) {
            float blo = b2s[flo + j], bhi = b2s[fhi + j];
            acc[0][j] = blo; acc[0][4 + j] = bhi;
            acc[1][j] = blo; acc[1][4 + j] = bhi;
        }
        #pragma unroll 4
        for (int k = 0; k < DIM_C; ++k) {
            float a0 = t1s[e0][k];
            float a1 = t1s[e0 + 1][k];
            float4 wl = *(const float4*)&W2s[k][flo];
            float4 wh = *(const float4*)&W2s[k][fhi];
            acc[0][0] += a0 * wl.x; acc[0][1] += a0 * wl.y;
            acc[0][2] += a0 * wl.z; acc[0][3] += a0 * wl.w;
            acc[0][4] += a0 * wh.x; acc[0][5] += a0 * wh.y;
            acc[0][6] += a0 * wh.z; acc[0][7] += a0 * wh.w;
            acc[1][0] += a1 * wl.x; acc[1][1] += a1 * wl.y;
            acc[1][2] += a1 * wl.z; acc[1][3] += a1 * wl.w;
            acc[1][4] += a1 * wh.x; acc[1][5] += a1 * wh.y;
            acc[1][6] += a1 * wh.z; acc[1][7] += a1 * wh.w;
        }

        // ---- epilogue: relu -> BN -> msg = relu(x[src]+e) -> atomic scatter ----
        #pragma unroll
        for (int ei = 0; ei < 2; ++ei) {
            int e = e0 + ei;
            if (e < count) {
                int s = srcs[e], d = dsts[e];
                float4 xl = *(const float4*)&x[s * DIM_C + flo];
                float4 xh = *(const float4*)&x[s * DIM_C + fhi];
                float xv[8] = {xl.x, xl.y, xl.z, xl.w, xh.x, xh.y, xh.z, xh.w};
                #pragma unroll
                for (int j = 0; j < 8; ++j) {
                    int f = (j < 4) ? (flo + j) : (fhi + j - 4);
                    float v = fmaxf(acc[ei][j], 0.f) * bscs[f] + bshs[f];
                    v = fmaxf(xv[j] + v, 0.f);
                    atomicAdd(&agg[d * DIM_C + f], v);
                }
            }
        }
        __syncthreads();
    }
}

// -------------------------------------------------------------------------
// Node MLP kernel: out = epi( (in0 [+ in1]) @ W + b ), epi = relu [-> BN]
// Same register tiling as edge stage2. Safe for out == in0 or out == in1
// (tile is fully read into LDS before the epilogue writes it back).
// -------------------------------------------------------------------------
__global__ __launch_bounds__(512)
void node_kernel(const float* __restrict__ in0,
                 const float* __restrict__ in1,   // nullable
                 const float* __restrict__ W,
                 const float* __restrict__ b,
                 const float* __restrict__ bng,
                 const float* __restrict__ bnb,
                 const float* __restrict__ bnrm,
                 const float* __restrict__ bnrv,
                 float* __restrict__ out,
                 int nrows, int use_bn)
{
    __shared__ float Ws[DIM_C][DIM_C];       // 64 KB
    __shared__ float hsv[ETILE][TPAD];       // 33.8 KB
    __shared__ float bs[DIM_C], bscs[DIM_C], bshs[DIM_C];

    const int tid = threadIdx.x;
    for (int i = tid; i < DIM_C * DIM_C / 4; i += 512)
        ((float4*)Ws)[i] = ((const float4*)W)[i];
    if (tid < DIM_C) {
        bs[tid] = b[tid];
        if (use_bn) {
            float sc = bng[tid] * rsqrtf(bnrv[tid] + BN_EPS_C);
            bscs[tid] = sc;
            bshs[tid] = bnb[tid] - bnrm[tid] * sc;
        } else {
            bscs[tid] = 1.f;
            bshs[tid] = 0.f;
        }
    }
    __syncthreads();

    const int fg  = tid & 15;
    const int eg  = tid >> 4;
    const int r0  = eg * 2;
    const int flo = fg * 4;
    const int fhi = flo + 64;

    const int ntiles = (nrows + ETILE - 1) / ETILE;
    for (int t = blockIdx.x; t < ntiles; t += gridDim.x) {
        const int base  = t * ETILE;
        const int count = min(ETILE, nrows - base);

        for (int i4 = tid; i4 < ETILE * DIM_C / 4; i4 += 512) {
            int r = i4 >> 5;
            if (r < count) {
                int c = (i4 & 31) * 4;
                float4 v = *(const float4*)&in0[(base + r) * DIM_C + c];
                if (in1) {
                    float4 a = *(const float4*)&in1[(base + r) * DIM_C + c];
                    v.x += a.x; v.y += a.y; v.z += a.z; v.w += a.w;
                }
                *(float4*)&hsv[r][c] = v;
            }
        }
        __syncthreads();

        float acc[2][8];
        #pragma unroll
        for (int j = 0; j < 4; ++j) {
            float blo = bs[flo + j], bhi = bs[fhi + j];
            acc[0][j] = blo; acc[0][4 + j] = bhi;
            acc[1][j] = blo; acc[1][4 + j] = bhi;
        }
        #pragma unroll 4
        for (int k = 0; k < DIM_C; ++k) {
            float a0 = hsv[r0][k];
            float a1 = hsv[r0 + 1][k];
            float4 wl = *(const float4*)&Ws[k][flo];
            float4 wh = *(const float4*)&Ws[k][fhi];
            acc[0][0] += a0 * wl.x; acc[0][1] += a0 * wl.y;
            acc[0][2] += a0 * wl.z; acc[0][3] += a0 * wl.w;
            acc[0][4] += a0 * wh.x; acc[0][5] += a0 * wh.y;
            acc[0][6] += a0 * wh.z; acc[0][7] += a0 * wh.w;
            acc[1][0] += a1 * wl.x; acc[1][1] += a1 * wl.y;
            acc[1][2] += a1 * wl.z; acc[1][3] += a1 * wl.w;
            acc[1][4] += a1 * wh.x; acc[1][5] += a1 * wh.y;
            acc[1][6] += a1 * wh.z; acc[1][7] += a1 * wh.w;
        }

        #pragma unroll
        for (int ei = 0; ei < 2; ++ei) {
            int r = r0 + ei;
            if (r < count) {
                float4 ol, oh;
                float* po = (float*)&ol;
                float* ph = (float*)&oh;
                #pragma unroll
                for (int j = 0; j < 4; ++j) {
                    po[j] = fmaxf(acc[ei][j], 0.f) * bscs[flo + j] + bshs[flo + j];
                    ph[j] = fmaxf(acc[ei][4 + j], 0.f) * bscs[fhi + j] + bshs[fhi + j];
                }
                *(float4*)&out[(base + r) * DIM_C + flo] = ol;
                *(float4*)&out[(base + r) * DIM_C + fhi] = oh;
            }
        }
        __syncthreads();
    }
}

// -------------------------------------------------------------------------
// Global mean-pool accumulation: atomic adds into per-graph sums + counts.
// -------------------------------------------------------------------------
__global__ void pool_kernel(const float* __restrict__ x,
                            const int* __restrict__ batch,
                            float* __restrict__ sums,
                            float* __restrict__ cnts)
{
    const int total = N_NODES_C * DIM_C;
    for (int idx = blockIdx.x * blockDim.x + threadIdx.x; idx < total;
         idx += gridDim.x * blockDim.x) {
        int n = idx >> 7;
        int f = idx & 127;
        int g = batch[n];
        atomicAdd(&sums[g * DIM_C + f], x[idx]);
        if (f == 0) atomicAdd(&cnts[g], 1.0f);
    }
}

// -------------------------------------------------------------------------
// Readout head: pooled -> relu(lin1) -> lin2 -> log_softmax. One block/graph.
// -------------------------------------------------------------------------
__global__ __launch_bounds__(128)
void head_kernel(const float* __restrict__ sums,
                 const float* __restrict__ cnts,
                 const float* __restrict__ l1w,
                 const float* __restrict__ l1b,
                 const float* __restrict__ l2w,
                 const float* __restrict__ l2b,
                 float* __restrict__ out)
{
    const int g = blockIdx.x;
    const int tid = threadIdx.x;
    __shared__ float ps[DIM_C];
    __shared__ float hs[DIM_C];
    __shared__ float lg[N_CLASSES_C];
    __shared__ float lse;

    float c = fmaxf(cnts[g], 1.0f);
    ps[tid] = sums[g * DIM_C + tid] / c;
    __syncthreads();

    float a = l1b[tid];
    for (int k = 0; k < DIM_C; ++k)
        a += ps[k] * l1w[k * DIM_C + tid];
    hs[tid] = fmaxf(a, 0.f);
    __syncthreads();

    if (tid < N_CLASSES_C) {
        float s = l2b[tid];
        for (int f = 0; f < DIM_C; ++f)
            s += hs[f] * l2w[f * N_CLASSES_C + tid];
        lg[tid] = s;
    }
    __syncthreads();

    if (tid == 0) {
        float m = lg[0];
        for (int cc = 1; cc < N_CLASSES_C; ++cc) m = fmaxf(m, lg[cc]);
        float s = 0.f;
        for (int cc = 0; cc < N_CLASSES_C; ++cc) s += expf(lg[cc] - m);
        lse = m + logf(s);
    }
    __syncthreads();

    if (tid < N_CLASSES_C)
        out[g * N_CLASSES_C + tid] = lg[tid] - lse;
}

// -------------------------------------------------------------------------
extern "C" void kernel_launch(void* const* d_in, const int* in_sizes, int n_in,
                              void* d_out, int out_size, void* d_ws, size_t ws_size,
                              hipStream_t stream)
{
    const float* x         = (const float*)d_in[0];
    const float* edge_attr = (const float*)d_in[1];
    const int*   ei        = (const int*)d_in[2];
    const int*   batch     = (const int*)d_in[3];
    const float* ee_w1     = (const float*)d_in[4];
    const float* ee_b1     = (const float*)d_in[5];
    const float* ee_w2     = (const float*)d_in[6];
    const float* ee_b2     = (const float*)d_in[7];
    const float* ee_bn_g   = (const float*)d_in[8];
    const float* ee_bn_b   = (const float*)d_in[9];
    const float* ee_bn_rm  = (const float*)d_in[10];
    const float* ee_bn_rv  = (const float*)d_in[11];
    const float* mlp_w1    = (const float*)d_in[12];
    const float* mlp_b1    = (const float*)d_in[13];
    const float* mlp_w2    = (const float*)d_in[14];
    const float* mlp_b2    = (const float*)d_in[15];
    const float* mlp_bn_g  = (const float*)d_in[16];
    const float* mlp_bn_b  = (const float*)d_in[17];
    const float* mlp_bn_rm = (const float*)d_in[18];
    const float* mlp_bn_rv = (const float*)d_in[19];
    const float* lin1_w    = (const float*)d_in[20];
    const float* lin1_b    = (const float*)d_in[21];
    const float* lin2_w    = (const float*)d_in[22];
    const float* lin2_b    = (const float*)d_in[23];
    float* out = (float*)d_out;

    const int* src = ei;
    const int* dst = ei + N_EDGES_C;

    // workspace layout (floats)
    float* x_cur = (float*)d_ws;                       // 6,400,000
    float* agg   = x_cur + (size_t)N_NODES_C * DIM_C;  // 6,400,000 (also h1)
    float* sums  = agg + (size_t)N_NODES_C * DIM_C;    // 65,536
    float* cnts  = sums + (size_t)N_GRAPHS_C * DIM_C;  // 512

    const float* xin = x;
    for (int i = 0; i < N_LAYERS_C; ++i) {
        hipMemsetAsync(agg, 0, (size_t)N_NODES_C * DIM_C * sizeof(float), stream);
        edge_kernel<<<256, 512, 0, stream>>>(
            edge_attr, xin, src, dst,
            ee_w1 + i * EDGE_DIM_C * DIM_C, ee_b1 + i * DIM_C,
            ee_w2 + i * DIM_C * DIM_C,      ee_b2 + i * DIM_C,
            ee_bn_g + i * DIM_C, ee_bn_b + i * DIM_C,
            ee_bn_rm + i * DIM_C, ee_bn_rv + i * DIM_C,
            agg);
        // h1 = relu((x + agg) @ W1 + b1), written in-place over agg
        node_kernel<<<256, 512, 0, stream>>>(
            xin, agg,
            mlp_w1 + i * DIM_C * DIM_C, mlp_b1 + i * DIM_C,
            nullptr, nullptr, nullptr, nullptr,
            agg, N_NODES_C, 0);
        // x_cur = bn(relu(h1 @ W2 + b2))
        node_kernel<<<256, 512, 0, stream>>>(
            agg, nullptr,
            mlp_w2 + i * DIM_C * DIM_C, mlp_b2 + i * DIM_C,
            mlp_bn_g + i * DIM_C, mlp_bn_b + i * DIM_C,
            mlp_bn_rm + i * DIM_C, mlp_bn_rv + i * DIM_C,
            x_cur, N_NODES_C, 1);
        xin = x_cur;
    }

    hipMemsetAsync(sums, 0,
                   ((size_t)N_GRAPHS_C * DIM_C + N_GRAPHS_C) * sizeof(float), stream);
    pool_kernel<<<1024, 256, 0, stream>>>(xin, batch, sums, cnts);
    head_kernel<<<N_GRAPHS_C, 128, 0, stream>>>(sums, cnts, lin1_w, lin1_b,
                                                lin2_w, lin2_b, out);
}

// Round 2
// 1880.152 us; speedup vs baseline: 1.6283x; 1.6283x over previous
//
#include <hip/hip_runtime.h>

#define N_NODES_C 50000
#define N_EDGES_C 500000
#define EDGE_DIM_C 16
#define DIM_C 128
#define N_LAYERS_C 3
#define N_GRAPHS_C 512
#define N_CLASSES_C 10
#define BN_EPS_C 1e-5f

#define ETILE 64
#define TPAD 132
#define CHUNK_C 125000   // 4 chunk passes per layer; emb buf = 32 MB bf16

// fp32 -> bf16 round-to-nearest-even
__device__ inline unsigned short f2bf(float f) {
    union { float f; unsigned u; } v; v.f = f;
    unsigned r = v.u + 0x7FFF + ((v.u >> 16) & 1);
    return (unsigned short)(r >> 16);
}
__device__ inline float bf2f(unsigned short h) {
    union { unsigned u; float f; } v; v.u = ((unsigned)h) << 16;
    return v.f;
}

// -------------------------------------------------------------------------
// Preprocessing: counting sort of edges by dst (once per launch)
// -------------------------------------------------------------------------
__global__ void hist_kernel(const int* __restrict__ dst, int* __restrict__ cnt)
{
    int e = blockIdx.x * blockDim.x + threadIdx.x;
    if (e < N_EDGES_C) atomicAdd(&cnt[dst[e]], 1);
}

// single-block scan: offsets[0]=0, offsets[i+1]=incl_sum(cnt[0..i]); cursor[i]=excl
__global__ __launch_bounds__(1024)
void scan_kernel(const int* __restrict__ cnt,
                 int* __restrict__ offsets,
                 int* __restrict__ cursor)
{
    __shared__ int buf[1024];
    __shared__ int carry;
    const int tid = threadIdx.x;
    if (tid == 0) { carry = 0; offsets[0] = 0; }
    __syncthreads();
    for (int base = 0; base < N_NODES_C; base += 1024) {
        int i = base + tid;
        int v = (i < N_NODES_C) ? cnt[i] : 0;
        buf[tid] = v;
        __syncthreads();
        for (int off = 1; off < 1024; off <<= 1) {
            int t = (tid >= off) ? buf[tid - off] : 0;
            __syncthreads();
            buf[tid] += t;
            __syncthreads();
        }
        if (i < N_NODES_C) {
            int incl = carry + buf[tid];
            offsets[i + 1] = incl;
            cursor[i] = incl - v;
        }
        __syncthreads();
        if (tid == 0) carry += buf[1023];
        __syncthreads();
    }
}

__global__ void scatter_kernel(const int* __restrict__ src,
                               const int* __restrict__ dst,
                               const float* __restrict__ ea,
                               int* __restrict__ cursor,
                               int* __restrict__ srcPerm,
                               float* __restrict__ eaPerm)
{
    int e = blockIdx.x * blockDim.x + threadIdx.x;
    if (e >= N_EDGES_C) return;
    int pos = atomicAdd(&cursor[dst[e]], 1);
    srcPerm[pos] = src[e];
    const float4* in = (const float4*)&ea[(size_t)e * EDGE_DIM_C];
    float4* out = (float4*)&eaPerm[(size_t)pos * EDGE_DIM_C];
    out[0] = in[0]; out[1] = in[1]; out[2] = in[2]; out[3] = in[3];
}

// -------------------------------------------------------------------------
// Edge embedding GEMM: emb = bf16( BN(relu(relu(eaPerm@W1+b1)@W2+b2)) )
// over sorted-edge chunk [c0,c1). Pure GEMM, no gather, no atomics.
// -------------------------------------------------------------------------
__global__ __launch_bounds__(512)
void emb_kernel(const float* __restrict__ eaPerm,
                const float* __restrict__ W1,
                const float* __restrict__ b1,
                const float* __restrict__ W2,
                const float* __restrict__ b2,
                const float* __restrict__ bng,
                const float* __restrict__ bnb,
                const float* __restrict__ bnrm,
                const float* __restrict__ bnrv,
                unsigned short* __restrict__ emb,
                int c0, int c1)
{
    __shared__ float W1s[EDGE_DIM_C][DIM_C];
    __shared__ float W2s[DIM_C][DIM_C];
    __shared__ float t1s[ETILE][TPAD];
    __shared__ float eas[ETILE][EDGE_DIM_C];
    __shared__ float b1s[DIM_C], b2s[DIM_C], bscs[DIM_C], bshs[DIM_C];

    const int tid = threadIdx.x;
    for (int i = tid; i < EDGE_DIM_C * DIM_C / 4; i += 512)
        ((float4*)W1s)[i] = ((const float4*)W1)[i];
    for (int i = tid; i < DIM_C * DIM_C / 4; i += 512)
        ((float4*)W2s)[i] = ((const float4*)W2)[i];
    if (tid < DIM_C) {
        b1s[tid] = b1[tid];
        b2s[tid] = b2[tid];
        float sc = bng[tid] * rsqrtf(bnrv[tid] + BN_EPS_C);
        bscs[tid] = sc;
        bshs[tid] = bnb[tid] - bnrm[tid] * sc;
    }
    __syncthreads();

    const int fg  = tid & 15;
    const int eg  = tid >> 4;
    const int e0  = eg * 2;
    const int flo = fg * 4;
    const int fhi = flo + 64;

    const int nEdges = c1 - c0;
    const int ntiles = (nEdges + ETILE - 1) / ETILE;
    for (int t = blockIdx.x; t < ntiles; t += gridDim.x) {
        const int base  = t * ETILE;
        const int count = min(ETILE, nEdges - base);

        for (int i = tid; i < count * EDGE_DIM_C; i += 512)
            ((float*)eas)[i] = eaPerm[(size_t)(c0 + base) * EDGE_DIM_C + i];
        __syncthreads();

        for (int idx = tid; idx < ETILE * DIM_C; idx += 512) {
            int e = idx >> 7;
            if (e < count) {
                int f = idx & 127;
                float a = b1s[f];
                #pragma unroll
                for (int k = 0; k < EDGE_DIM_C; ++k)
                    a += eas[e][k] * W1s[k][f];
                t1s[e][f] = fmaxf(a, 0.f);
            }
        }
        __syncthreads();

        float acc[2][8];
        #pragma unroll
        for (int j = 0; j < 4; ++j) {
            float blo = b2s[flo + j], bhi = b2s[fhi + j];
            acc[0][j] = blo; acc[0][4 + j] = bhi;
            acc[1][j] = blo; acc[1][4 + j] = bhi;
        }
        #pragma unroll 4
        for (int k = 0; k < DIM_C; ++k) {
            float a0 = t1s[e0][k];
            float a1 = t1s[e0 + 1][k];
            float4 wl = *(const float4*)&W2s[k][flo];
            float4 wh = *(const float4*)&W2s[k][fhi];
            acc[0][0] += a0 * wl.x; acc[0][1] += a0 * wl.y;
            acc[0][2] += a0 * wl.z; acc[0][3] += a0 * wl.w;
            acc[0][4] += a0 * wh.x; acc[0][5] += a0 * wh.y;
            acc[0][6] += a0 * wh.z; acc[0][7] += a0 * wh.w;
            acc[1][0] += a1 * wl.x; acc[1][1] += a1 * wl.y;
            acc[1][2] += a1 * wl.z; acc[1][3] += a1 * wl.w;
            acc[1][4] += a1 * wh.x; acc[1][5] += a1 * wh.y;
            acc[1][6] += a1 * wh.z; acc[1][7] += a1 * wh.w;
        }

        #pragma unroll
        for (int ei = 0; ei < 2; ++ei) {
            int e = e0 + ei;
            if (e < count) {
                ushort4 lo4, hi4;
                unsigned short* pl = (unsigned short*)&lo4;
                unsigned short* ph = (unsigned short*)&hi4;
                #pragma unroll
                for (int j = 0; j < 4; ++j) {
                    pl[j] = f2bf(fmaxf(acc[ei][j], 0.f) * bscs[flo + j] + bshs[flo + j]);
                    ph[j] = f2bf(fmaxf(acc[ei][4 + j], 0.f) * bscs[fhi + j] + bshs[fhi + j]);
                }
                size_t row = (size_t)(base + e) * DIM_C;
                *(ushort4*)&emb[row + flo] = lo4;
                *(ushort4*)&emb[row + fhi] = hi4;
            }
        }
        __syncthreads();
    }
}

// -------------------------------------------------------------------------
// CSR aggregation (atomic-free): 32 lanes per node, 8 nodes per block.
// agg[n] (+)= sum over edges pos in [off[n],off[n+1]) ∩ [c0,c1) of
//             relu(x[srcPerm[pos]] + emb[pos-c0])
// first pass (c0==0) initializes agg for ALL nodes.
// -------------------------------------------------------------------------
__global__ __launch_bounds__(256)
void agg_kernel(const unsigned short* __restrict__ emb,
                const float* __restrict__ x,
                const int* __restrict__ srcPerm,
                const int* __restrict__ offsets,
                float* __restrict__ agg,
                int c0, int c1, int first)
{
    const int slot = threadIdx.x >> 5;
    const int l    = threadIdx.x & 31;
    const int n = blockIdx.x * 8 + slot;
    if (n >= N_NODES_C) return;

    int lo = offsets[n], hi = offsets[n + 1];
    lo = max(lo, c0); hi = min(hi, c1);

    float4 s = make_float4(0.f, 0.f, 0.f, 0.f);
    const bool any = lo < hi;
    for (int pos = lo; pos < hi; ++pos) {
        int srcn = srcPerm[pos];
        ushort4 eb = *(const ushort4*)&emb[(size_t)(pos - c0) * DIM_C + l * 4];
        float4 xv = *(const float4*)&x[(size_t)srcn * DIM_C + l * 4];
        s.x += fmaxf(xv.x + bf2f(eb.x), 0.f);
        s.y += fmaxf(xv.y + bf2f(eb.y), 0.f);
        s.z += fmaxf(xv.z + bf2f(eb.z), 0.f);
        s.w += fmaxf(xv.w + bf2f(eb.w), 0.f);
    }

    float4* ap = (float4*)&agg[(size_t)n * DIM_C + l * 4];
    if (first) {
        *ap = s;
    } else if (any) {
        float4 o = *ap;
        o.x += s.x; o.y += s.y; o.z += s.z; o.w += s.w;
        *ap = o;
    }
}

// -------------------------------------------------------------------------
// Node MLP kernel (unchanged from round 1)
// -------------------------------------------------------------------------
__global__ __launch_bounds__(512)
void node_kernel(const float* __restrict__ in0,
                 const float* __restrict__ in1,
                 const float* __restrict__ W,
                 const float* __restrict__ b,
                 const float* __restrict__ bng,
                 const float* __restrict__ bnb,
                 const float* __restrict__ bnrm,
                 const float* __restrict__ bnrv,
                 float* __restrict__ out,
                 int nrows, int use_bn)
{
    __shared__ float Ws[DIM_C][DIM_C];
    __shared__ float hsv[ETILE][TPAD];
    __shared__ float bs[DIM_C], bscs[DIM_C], bshs[DIM_C];

    const int tid = threadIdx.x;
    for (int i = tid; i < DIM_C * DIM_C / 4; i += 512)
        ((float4*)Ws)[i] = ((const float4*)W)[i];
    if (tid < DIM_C) {
        bs[tid] = b[tid];
        if (use_bn) {
            float sc = bng[tid] * rsqrtf(bnrv[tid] + BN_EPS_C);
            bscs[tid] = sc;
            bshs[tid] = bnb[tid] - bnrm[tid] * sc;
        } else {
            bscs[tid] = 1.f;
            bshs[tid] = 0.f;
        }
    }
    __syncthreads();

    const int fg  = tid & 15;
    const int eg  = tid >> 4;
    const int r0  = eg * 2;
    const int flo = fg * 4;
    const int fhi = flo + 64;

    const int ntiles = (nrows + ETILE - 1) / ETILE;
    for (int t = blockIdx.x; t < ntiles; t += gridDim.x) {
        const int base  = t * ETILE;
        const int count = min(ETILE, nrows - base);

        for (int i4 = tid; i4 < ETILE * DIM_C / 4; i4 += 512) {
            int r = i4 >> 5;
            if (r < count) {
                int c = (i4 & 31) * 4;
                float4 v = *(const float4*)&in0[(size_t)(base + r) * DIM_C + c];
                if (in1) {
                    float4 a = *(const float4*)&in1[(size_t)(base + r) * DIM_C + c];
                    v.x += a.x; v.y += a.y; v.z += a.z; v.w += a.w;
                }
                *(float4*)&hsv[r][c] = v;
            }
        }
        __syncthreads();

        float acc[2][8];
        #pragma unroll
        for (int j = 0; j < 4; ++j) {
            float blo = bs[flo + j], bhi = bs[fhi + j];
            acc[0][j] = blo; acc[0][4 + j] = bhi;
            acc[1][j] = blo; acc[1][4 + j] = bhi;
        }
        #pragma unroll 4
        for (int k = 0; k < DIM_C; ++k) {
            float a0 = hsv[r0][k];
            float a1 = hsv[r0 + 1][k];
            float4 wl = *(const float4*)&Ws[k][flo];
            float4 wh = *(const float4*)&Ws[k][fhi];
            acc[0][0] += a0 * wl.x; acc[0][1] += a0 * wl.y;
            acc[0][2] += a0 * wl.z; acc[0][3] += a0 * wl.w;
            acc[0][4] += a0 * wh.x; acc[0][5] += a0 * wh.y;
            acc[0][6] += a0 * wh.z; acc[0][7] += a0 * wh.w;
            acc[1][0] += a1 * wl.x; acc[1][1] += a1 * wl.y;
            acc[1][2] += a1 * wl.z; acc[1][3] += a1 * wl.w;
            acc[1][4] += a1 * wh.x; acc[1][5] += a1 * wh.y;
            acc[1][6] += a1 * wh.z; acc[1][7] += a1 * wh.w;
        }

        #pragma unroll
        for (int ei = 0; ei < 2; ++ei) {
            int r = r0 + ei;
            if (r < count) {
                float4 ol, oh;
                float* po = (float*)&ol;
                float* ph = (float*)&oh;
                #pragma unroll
                for (int j = 0; j < 4; ++j) {
                    po[j] = fmaxf(acc[ei][j], 0.f) * bscs[flo + j] + bshs[flo + j];
                    ph[j] = fmaxf(acc[ei][4 + j], 0.f) * bscs[fhi + j] + bshs[fhi + j];
                }
                *(float4*)&out[(size_t)(base + r) * DIM_C + flo] = ol;
                *(float4*)&out[(size_t)(base + r) * DIM_C + fhi] = oh;
            }
        }
        __syncthreads();
    }
}

// -------------------------------------------------------------------------
__global__ void pool_kernel(const float* __restrict__ x,
                            const int* __restrict__ batch,
                            float* __restrict__ sums,
                            float* __restrict__ cnts)
{
    const int total = N_NODES_C * DIM_C;
    for (int idx = blockIdx.x * blockDim.x + threadIdx.x; idx < total;
         idx += gridDim.x * blockDim.x) {
        int n = idx >> 7;
        int f = idx & 127;
        int g = batch[n];
        atomicAdd(&sums[g * DIM_C + f], x[idx]);
        if (f == 0) atomicAdd(&cnts[g], 1.0f);
    }
}

__global__ __launch_bounds__(128)
void head_kernel(const float* __restrict__ sums,
                 const float* __restrict__ cnts,
                 const float* __restrict__ l1w,
                 const float* __restrict__ l1b,
                 const float* __restrict__ l2w,
                 const float* __restrict__ l2b,
                 float* __restrict__ out)
{
    const int g = blockIdx.x;
    const int tid = threadIdx.x;
    __shared__ float ps[DIM_C];
    __shared__ float hs[DIM_C];
    __shared__ float lg[N_CLASSES_C];
    __shared__ float lse;

    float c = fmaxf(cnts[g], 1.0f);
    ps[tid] = sums[g * DIM_C + tid] / c;
    __syncthreads();

    float a = l1b[tid];
    for (int k = 0; k < DIM_C; ++k)
        a += ps[k] * l1w[k * DIM_C + tid];
    hs[tid] = fmaxf(a, 0.f);
    __syncthreads();

    if (tid < N_CLASSES_C) {
        float s = l2b[tid];
        for (int f = 0; f < DIM_C; ++f)
            s += hs[f] * l2w[f * N_CLASSES_C + tid];
        lg[tid] = s;
    }
    __syncthreads();

    if (tid == 0) {
        float m = lg[0];
        for (int cc = 1; cc < N_CLASSES_C; ++cc) m = fmaxf(m, lg[cc]);
        float s = 0.f;
        for (int cc = 0; cc < N_CLASSES_C; ++cc) s += expf(lg[cc] - m);
        lse = m + logf(s);
    }
    __syncthreads();

    if (tid < N_CLASSES_C)
        out[g * N_CLASSES_C + tid] = lg[tid] - lse;
}

// -------------------------------------------------------------------------
extern "C" void kernel_launch(void* const* d_in, const int* in_sizes, int n_in,
                              void* d_out, int out_size, void* d_ws, size_t ws_size,
                              hipStream_t stream)
{
    const float* x         = (const float*)d_in[0];
    const float* edge_attr = (const float*)d_in[1];
    const int*   ei        = (const int*)d_in[2];
    const int*   batch     = (const int*)d_in[3];
    const float* ee_w1     = (const float*)d_in[4];
    const float* ee_b1     = (const float*)d_in[5];
    const float* ee_w2     = (const float*)d_in[6];
    const float* ee_b2     = (const float*)d_in[7];
    const float* ee_bn_g   = (const float*)d_in[8];
    const float* ee_bn_b   = (const float*)d_in[9];
    const float* ee_bn_rm  = (const float*)d_in[10];
    const float* ee_bn_rv  = (const float*)d_in[11];
    const float* mlp_w1    = (const float*)d_in[12];
    const float* mlp_b1    = (const float*)d_in[13];
    const float* mlp_w2    = (const float*)d_in[14];
    const float* mlp_b2    = (const float*)d_in[15];
    const float* mlp_bn_g  = (const float*)d_in[16];
    const float* mlp_bn_b  = (const float*)d_in[17];
    const float* mlp_bn_rm = (const float*)d_in[18];
    const float* mlp_bn_rv = (const float*)d_in[19];
    const float* lin1_w    = (const float*)d_in[20];
    const float* lin1_b    = (const float*)d_in[21];
    const float* lin2_w    = (const float*)d_in[22];
    const float* lin2_b    = (const float*)d_in[23];
    float* out = (float*)d_out;

    const int* src = ei;
    const int* dst = ei + N_EDGES_C;

    // ---- workspace layout (bytes; ~118 MB) ----
    char* w = (char*)d_ws;
    float* x_cur = (float*)w;          w += (size_t)N_NODES_C * DIM_C * 4;      // 25.6 MB
    float* agg   = (float*)w;          w += (size_t)N_NODES_C * DIM_C * 4;      // 25.6 MB
    float* eaPerm = (float*)w;         w += (size_t)N_EDGES_C * EDGE_DIM_C * 4; // 32 MB
    unsigned short* emb = (unsigned short*)w; w += (size_t)CHUNK_C * DIM_C * 2; // 32 MB
    int* srcPerm = (int*)w;            w += (size_t)N_EDGES_C * 4;              // 2 MB
    int* cnt     = (int*)w;            w += 200704;
    int* offsets = (int*)w;            w += 200704;
    int* cursor  = (int*)w;            w += 200704;
    float* sums  = (float*)w;          w += (size_t)N_GRAPHS_C * DIM_C * 4;
    float* cnts  = (float*)w;          w += N_GRAPHS_C * 4;

    // ---- preprocess: counting sort by dst ----
    hipMemsetAsync(cnt, 0, N_NODES_C * sizeof(int), stream);
    hist_kernel<<<(N_EDGES_C + 255) / 256, 256, 0, stream>>>(dst, cnt);
    scan_kernel<<<1, 1024, 0, stream>>>(cnt, offsets, cursor);
    scatter_kernel<<<(N_EDGES_C + 255) / 256, 256, 0, stream>>>(
        src, dst, edge_attr, cursor, srcPerm, eaPerm);

    const float* xin = x;
    for (int i = 0; i < N_LAYERS_C; ++i) {
        for (int c0 = 0; c0 < N_EDGES_C; c0 += CHUNK_C) {
            int c1 = min(c0 + CHUNK_C, N_EDGES_C);
            emb_kernel<<<256, 512, 0, stream>>>(
                eaPerm,
                ee_w1 + i * EDGE_DIM_C * DIM_C, ee_b1 + i * DIM_C,
                ee_w2 + i * DIM_C * DIM_C,      ee_b2 + i * DIM_C,
                ee_bn_g + i * DIM_C, ee_bn_b + i * DIM_C,
                ee_bn_rm + i * DIM_C, ee_bn_rv + i * DIM_C,
                emb, c0, c1);
            agg_kernel<<<(N_NODES_C + 7) / 8, 256, 0, stream>>>(
                emb, xin, srcPerm, offsets, agg, c0, c1, c0 == 0 ? 1 : 0);
        }
        node_kernel<<<256, 512, 0, stream>>>(
            xin, agg,
            mlp_w1 + i * DIM_C * DIM_C, mlp_b1 + i * DIM_C,
            nullptr, nullptr, nullptr, nullptr,
            agg, N_NODES_C, 0);
        node_kernel<<<256, 512, 0, stream>>>(
            agg, nullptr,
            mlp_w2 + i * DIM_C * DIM_C, mlp_b2 + i * DIM_C,
            mlp_bn_g + i * DIM_C, mlp_bn_b + i * DIM_C,
            mlp_bn_rm + i * DIM_C, mlp_bn_rv + i * DIM_C,
            x_cur, N_NODES_C, 1);
        xin = x_cur;
    }

    hipMemsetAsync(sums, 0,
                   ((size_t)N_GRAPHS_C * DIM_C + N_GRAPHS_C) * sizeof(float), stream);
    pool_kernel<<<1024, 256, 0, stream>>>(xin, batch, sums, cnts);
    head_kernel<<<N_GRAPHS_C, 128, 0, stream>>>(sums, cnts, lin1_w, lin1_b,
                                                lin2_w, lin2_b, out);
}

// Round 3
// 964.894 us; speedup vs baseline: 3.1728x; 1.9486x over previous
//
#include <hip/hip_runtime.h>

#define N_NODES_C 50000
#define N_EDGES_C 500000
#define EDGE_DIM_C 16
#define DIM_C 128
#define N_LAYERS_C 3
#define N_GRAPHS_C 512
#define N_CLASSES_C 10
#define BN_EPS_C 1e-5f

#define CHUNK_C 125000   // 4 chunk passes per layer; emb buf = 32 MB bf16

typedef short bf16x8 __attribute__((ext_vector_type(8)));
typedef float f32x4  __attribute__((ext_vector_type(4)));

__device__ inline unsigned cvt_pk_bf16(float a, float b) {
    unsigned r;
    asm("v_cvt_pk_bf16_f32 %0, %1, %2" : "=v"(r) : "v"(a), "v"(b));
    return r;
}
__device__ inline float bf2f(unsigned short h) {
    union { unsigned u; float f; } v; v.u = ((unsigned)h) << 16;
    return v.f;
}
__device__ inline bf16x8 pack8(const float* f) {
    union { bf16x8 v; unsigned u[4]; } r;
    r.u[0] = cvt_pk_bf16(f[0], f[1]);
    r.u[1] = cvt_pk_bf16(f[2], f[3]);
    r.u[2] = cvt_pk_bf16(f[4], f[5]);
    r.u[3] = cvt_pk_bf16(f[6], f[7]);
    return r.v;
}

// -------------------------------------------------------------------------
// Preprocessing: counting sort of edges by dst (once per launch)
// -------------------------------------------------------------------------
__global__ void hist_kernel(const int* __restrict__ dst, int* __restrict__ cnt)
{
    int e = blockIdx.x * blockDim.x + threadIdx.x;
    if (e < N_EDGES_C) atomicAdd(&cnt[dst[e]], 1);
}

__global__ __launch_bounds__(1024)
void scan_kernel(const int* __restrict__ cnt,
                 int* __restrict__ offsets,
                 int* __restrict__ cursor)
{
    __shared__ int buf[1024];
    __shared__ int carry;
    const int tid = threadIdx.x;
    if (tid == 0) { carry = 0; offsets[0] = 0; }
    __syncthreads();
    for (int base = 0; base < N_NODES_C; base += 1024) {
        int i = base + tid;
        int v = (i < N_NODES_C) ? cnt[i] : 0;
        buf[tid] = v;
        __syncthreads();
        for (int off = 1; off < 1024; off <<= 1) {
            int t = (tid >= off) ? buf[tid - off] : 0;
            __syncthreads();
            buf[tid] += t;
            __syncthreads();
        }
        if (i < N_NODES_C) {
            int incl = carry + buf[tid];
            offsets[i + 1] = incl;
            cursor[i] = incl - v;
        }
        __syncthreads();
        if (tid == 0) carry += buf[1023];
        __syncthreads();
    }
}

__global__ void scatter_kernel(const int* __restrict__ src,
                               const int* __restrict__ dst,
                               const float* __restrict__ ea,
                               int* __restrict__ cursor,
                               int* __restrict__ srcPerm,
                               float* __restrict__ eaPerm)
{
    int e = blockIdx.x * blockDim.x + threadIdx.x;
    if (e >= N_EDGES_C) return;
    int pos = atomicAdd(&cursor[dst[e]], 1);
    srcPerm[pos] = src[e];
    const float4* in = (const float4*)&ea[(size_t)e * EDGE_DIM_C];
    float4* out = (float4*)&eaPerm[(size_t)pos * EDGE_DIM_C];
    out[0] = in[0]; out[1] = in[1]; out[2] = in[2]; out[3] = in[3];
}

// -------------------------------------------------------------------------
// Weight prep: transpose + bf16-convert all GEMM weights once per launch.
// blockIdx: 0..2 ee_w1 layers, 3..5 ee_w2, 6..8 mlp_w1, 9..11 mlp_w2.
// Output layout: WT[f][k] row-major (so B-fragments are contiguous 16B).
// -------------------------------------------------------------------------
__global__ __launch_bounds__(256)
void wprep_kernel(const float* __restrict__ ee_w1, const float* __restrict__ ee_w2,
                  const float* __restrict__ mlp_w1, const float* __restrict__ mlp_w2,
                  short* __restrict__ W1T, short* __restrict__ W2T,
                  short* __restrict__ MT1, short* __restrict__ MT2)
{
    int b = blockIdx.x;
    int l = b % 3;
    int which = b / 3;
    if (which == 0) {
        const float* in = ee_w1 + l * 16 * 128;
        short* outp = W1T + l * 128 * 16;
        for (int i = threadIdx.x; i < 2048; i += 256) {
            int f = i >> 4, k = i & 15;
            outp[i] = (short)(cvt_pk_bf16(in[k * 128 + f], 0.f) & 0xffff);
        }
    } else {
        const float* in = (which == 1 ? ee_w2 : which == 2 ? mlp_w1 : mlp_w2) + l * 128 * 128;
        short* outp = (which == 1 ? W2T : which == 2 ? MT1 : MT2) + l * 128 * 128;
        for (int i = threadIdx.x; i < 16384; i += 256) {
            int f = i >> 7, k = i & 127;
            outp[i] = (short)(cvt_pk_bf16(in[k * 128 + f], 0.f) & 0xffff);
        }
    }
}

// -------------------------------------------------------------------------
// MFMA edge-encoder: stage1 (16->128, K zero-padded to 32) -> bf16 t1 in
// swizzled LDS -> stage2 (128x128 MFMA) -> BN -> bf16 emb.
// Block = 256 thr = 4 waves; wave w: edge-tile et=w>>1 (64 edges), cols
// cg=w&1 (64 cols). W-fragments preloaded to registers from WT (global bf16).
// -------------------------------------------------------------------------
__global__ __launch_bounds__(256)
void emb_mfma(const float* __restrict__ eaPerm,
              const short* __restrict__ W1T, const float* __restrict__ b1,
              const short* __restrict__ W2T, const float* __restrict__ b2,
              const float* __restrict__ bng, const float* __restrict__ bnb,
              const float* __restrict__ bnrm, const float* __restrict__ bnrv,
              unsigned short* __restrict__ emb, int c0, int chunkN)
{
    __shared__ short t1s[2][64 * 128];   // bf16, XOR-swizzled, 32 KB

    const int tid  = threadIdx.x;
    const int lane = tid & 63;
    const int w    = tid >> 6;
    const int et   = w >> 1;
    const int cg   = w & 1;
    const int ln15 = lane & 15;
    const int g    = lane >> 4;
    const int colbase = cg * 64;

    // preload weight fragments (B-operands) into registers
    bf16x8 fw1[4], fw2[4][4];
    #pragma unroll
    for (int ct = 0; ct < 4; ++ct) {
        int f = colbase + ct * 16 + ln15;
        if (g < 2) fw1[ct] = *(const bf16x8*)&W1T[f * 16 + g * 8];
        else       fw1[ct] = (bf16x8){0,0,0,0,0,0,0,0};
        #pragma unroll
        for (int kb = 0; kb < 4; ++kb)
            fw2[ct][kb] = *(const bf16x8*)&W2T[f * 128 + kb * 32 + g * 8];
    }
    float b1v[4], b2v[4], scv[4], shv[4];
    #pragma unroll
    for (int ct = 0; ct < 4; ++ct) {
        int f = colbase + ct * 16 + ln15;
        b1v[ct] = b1[f]; b2v[ct] = b2[f];
        float sc = bng[f] * rsqrtf(bnrv[f] + BN_EPS_C);
        scv[ct] = sc; shv[ct] = bnb[f] - bnrm[f] * sc;
    }

    const int niter = (chunkN + 127) / 128;
    for (int it = blockIdx.x; it < niter; it += gridDim.x) {
        const int eb = it * 128 + et * 64;  // chunk-local base of this wave's tile

        // ---- stage1: t1 = relu(ea @ W1 + b1) via MFMA (K=16 padded) ----
        #pragma unroll
        for (int rt = 0; rt < 4; ++rt) {
            bf16x8 af;
            if (g < 2) {
                int erow = min(eb + rt * 16 + ln15, chunkN - 1);
                const float* p = &eaPerm[(size_t)(c0 + erow) * 16 + g * 8];
                float fv[8];
                *(float4*)&fv[0] = *(const float4*)p;
                *(float4*)&fv[4] = *(const float4*)(p + 4);
                af = pack8(fv);
            } else {
                af = (bf16x8){0,0,0,0,0,0,0,0};
            }
            #pragma unroll
            for (int ct = 0; ct < 4; ++ct) {
                f32x4 a1 = { b1v[ct], b1v[ct], b1v[ct], b1v[ct] };
                a1 = __builtin_amdgcn_mfma_f32_16x16x32_bf16(af, fw1[ct], a1, 0, 0, 0);
                int col = colbase + ct * 16 + ln15;
                #pragma unroll
                for (int r = 0; r < 4; ++r) {
                    int row = rt * 16 + g * 4 + r;
                    int idx = (row * 128 + col) ^ ((row & 15) << 3);
                    t1s[et][idx] = (short)(cvt_pk_bf16(fmaxf(a1[r], 0.f), 0.f) & 0xffff);
                }
            }
        }
        __syncthreads();

        // ---- stage2: acc = t1 @ W2 + b2 ----
        f32x4 acc[4][4];
        #pragma unroll
        for (int rt = 0; rt < 4; ++rt)
            #pragma unroll
            for (int ct = 0; ct < 4; ++ct)
                acc[rt][ct] = (f32x4){ b2v[ct], b2v[ct], b2v[ct], b2v[ct] };

        #pragma unroll
        for (int rt = 0; rt < 4; ++rt) {
            bf16x8 a[4];
            int row = rt * 16 + ln15;
            #pragma unroll
            for (int kb = 0; kb < 4; ++kb) {
                int idx = (row * 128 + kb * 32 + g * 8) ^ ((row & 15) << 3);
                a[kb] = *(const bf16x8*)&t1s[et][idx];
            }
            #pragma unroll
            for (int ct = 0; ct < 4; ++ct)
                #pragma unroll
                for (int kb = 0; kb < 4; ++kb)
                    acc[rt][ct] = __builtin_amdgcn_mfma_f32_16x16x32_bf16(
                        a[kb], fw2[ct][kb], acc[rt][ct], 0, 0, 0);
        }

        // ---- epilogue: relu -> BN -> bf16 emb ----
        #pragma unroll
        for (int rt = 0; rt < 4; ++rt)
            #pragma unroll
            for (int ct = 0; ct < 4; ++ct) {
                int col = colbase + ct * 16 + ln15;
                #pragma unroll
                for (int r = 0; r < 4; ++r) {
                    int row = eb + rt * 16 + g * 4 + r;
                    if (row < chunkN) {
                        float v = fmaxf(acc[rt][ct][r], 0.f) * scv[ct] + shv[ct];
                        emb[(size_t)row * 128 + col] =
                            (unsigned short)(cvt_pk_bf16(v, 0.f) & 0xffff);
                    }
                }
            }
        __syncthreads();
    }
}

// -------------------------------------------------------------------------
// MFMA node MLP: out = epi((in0 [+in1]) @ W + b); epi = relu [-> BN].
// Same wave decomposition as emb_mfma stage2. Safe in-place (LDS staged).
// -------------------------------------------------------------------------
__global__ __launch_bounds__(256)
void node_mfma(const float* __restrict__ in0, const float* __restrict__ in1,
               const short* __restrict__ WT, const float* __restrict__ bias,
               const float* __restrict__ bng, const float* __restrict__ bnb,
               const float* __restrict__ bnrm, const float* __restrict__ bnrv,
               float* __restrict__ out, int nrows, int use_bn)
{
    __shared__ short hs[2][64 * 128];

    const int tid  = threadIdx.x;
    const int lane = tid & 63;
    const int w    = tid >> 6;
    const int et   = w >> 1;
    const int cg   = w & 1;
    const int ln15 = lane & 15;
    const int g    = lane >> 4;
    const int colbase = cg * 64;

    bf16x8 fw[4][4];
    float bv[4], scv[4], shv[4];
    #pragma unroll
    for (int ct = 0; ct < 4; ++ct) {
        int f = colbase + ct * 16 + ln15;
        #pragma unroll
        for (int kb = 0; kb < 4; ++kb)
            fw[ct][kb] = *(const bf16x8*)&WT[f * 128 + kb * 32 + g * 8];
        bv[ct] = bias[f];
        if (use_bn) {
            float sc = bng[f] * rsqrtf(bnrv[f] + BN_EPS_C);
            scv[ct] = sc; shv[ct] = bnb[f] - bnrm[f] * sc;
        } else { scv[ct] = 1.f; shv[ct] = 0.f; }
    }

    const int niter = (nrows + 127) / 128;
    for (int it = blockIdx.x; it < niter; it += gridDim.x) {
        const int base = it * 128;

        // ---- stage inputs -> bf16 swizzled LDS ----
        for (int i = tid; i < 4096; i += 256) {
            int row = i >> 5;
            int c4  = (i & 31) * 4;
            int rr  = min(base + row, nrows - 1);
            float4 v = *(const float4*)&in0[(size_t)rr * 128 + c4];
            if (in1) {
                float4 a1 = *(const float4*)&in1[(size_t)rr * 128 + c4];
                v.x += a1.x; v.y += a1.y; v.z += a1.z; v.w += a1.w;
            }
            int e = row >> 6, r = row & 63;
            int idx = (r * 128 + c4) ^ ((r & 15) << 3);
            *(unsigned*)&hs[e][idx]     = cvt_pk_bf16(v.x, v.y);
            *(unsigned*)&hs[e][idx + 2] = cvt_pk_bf16(v.z, v.w);
        }
        __syncthreads();

        f32x4 acc[4][4];
        #pragma unroll
        for (int rt = 0; rt < 4; ++rt)
            #pragma unroll
            for (int ct = 0; ct < 4; ++ct)
                acc[rt][ct] = (f32x4){ bv[ct], bv[ct], bv[ct], bv[ct] };

        #pragma unroll
        for (int rt = 0; rt < 4; ++rt) {
            bf16x8 a[4];
            int row = rt * 16 + ln15;
            #pragma unroll
            for (int kb = 0; kb < 4; ++kb) {
                int idx = (row * 128 + kb * 32 + g * 8) ^ ((row & 15) << 3);
                a[kb] = *(const bf16x8*)&hs[et][idx];
            }
            #pragma unroll
            for (int ct = 0; ct < 4; ++ct)
                #pragma unroll
                for (int kb = 0; kb < 4; ++kb)
                    acc[rt][ct] = __builtin_amdgcn_mfma_f32_16x16x32_bf16(
                        a[kb], fw[ct][kb], acc[rt][ct], 0, 0, 0);
        }

        #pragma unroll
        for (int rt = 0; rt < 4; ++rt)
            #pragma unroll
            for (int ct = 0; ct < 4; ++ct) {
                int col = colbase + ct * 16 + ln15;
                #pragma unroll
                for (int r = 0; r < 4; ++r) {
                    int row = base + et * 64 + rt * 16 + g * 4 + r;
                    if (row < nrows) {
                        float v = fmaxf(acc[rt][ct][r], 0.f) * scv[ct] + shv[ct];
                        out[(size_t)row * 128 + col] = v;
                    }
                }
            }
        __syncthreads();
    }
}

// -------------------------------------------------------------------------
// CSR aggregation (atomic-free): 32 lanes per node, 8 nodes per block.
// -------------------------------------------------------------------------
__global__ __launch_bounds__(256)
void agg_kernel(const unsigned short* __restrict__ emb,
                const float* __restrict__ x,
                const int* __restrict__ srcPerm,
                const int* __restrict__ offsets,
                float* __restrict__ agg,
                int c0, int c1, int first)
{
    const int slot = threadIdx.x >> 5;
    const int l    = threadIdx.x & 31;
    const int n = blockIdx.x * 8 + slot;
    if (n >= N_NODES_C) return;

    int lo = offsets[n], hi = offsets[n + 1];
    lo = max(lo, c0); hi = min(hi, c1);

    float4 s = make_float4(0.f, 0.f, 0.f, 0.f);
    const bool any = lo < hi;
    for (int pos = lo; pos < hi; ++pos) {
        int srcn = srcPerm[pos];
        ushort4 eb = *(const ushort4*)&emb[(size_t)(pos - c0) * DIM_C + l * 4];
        float4 xv = *(const float4*)&x[(size_t)srcn * DIM_C + l * 4];
        s.x += fmaxf(xv.x + bf2f(eb.x), 0.f);
        s.y += fmaxf(xv.y + bf2f(eb.y), 0.f);
        s.z += fmaxf(xv.z + bf2f(eb.z), 0.f);
        s.w += fmaxf(xv.w + bf2f(eb.w), 0.f);
    }

    float4* ap = (float4*)&agg[(size_t)n * DIM_C + l * 4];
    if (first) {
        *ap = s;
    } else if (any) {
        float4 o = *ap;
        o.x += s.x; o.y += s.y; o.z += s.z; o.w += s.w;
        *ap = o;
    }
}

// -------------------------------------------------------------------------
__global__ void pool_kernel(const float* __restrict__ x,
                            const int* __restrict__ batch,
                            float* __restrict__ sums,
                            float* __restrict__ cnts)
{
    const int total = N_NODES_C * DIM_C;
    for (int idx = blockIdx.x * blockDim.x + threadIdx.x; idx < total;
         idx += gridDim.x * blockDim.x) {
        int n = idx >> 7;
        int f = idx & 127;
        int g = batch[n];
        atomicAdd(&sums[g * DIM_C + f], x[idx]);
        if (f == 0) atomicAdd(&cnts[g], 1.0f);
    }
}

__global__ __launch_bounds__(128)
void head_kernel(const float* __restrict__ sums,
                 const float* __restrict__ cnts,
                 const float* __restrict__ l1w,
                 const float* __restrict__ l1b,
                 const float* __restrict__ l2w,
                 const float* __restrict__ l2b,
                 float* __restrict__ out)
{
    const int g = blockIdx.x;
    const int tid = threadIdx.x;
    __shared__ float ps[DIM_C];
    __shared__ float hsx[DIM_C];
    __shared__ float lg[N_CLASSES_C];
    __shared__ float lse;

    float c = fmaxf(cnts[g], 1.0f);
    ps[tid] = sums[g * DIM_C + tid] / c;
    __syncthreads();

    float a = l1b[tid];
    for (int k = 0; k < DIM_C; ++k)
        a += ps[k] * l1w[k * DIM_C + tid];
    hsx[tid] = fmaxf(a, 0.f);
    __syncthreads();

    if (tid < N_CLASSES_C) {
        float s = l2b[tid];
        for (int f = 0; f < DIM_C; ++f)
            s += hsx[f] * l2w[f * N_CLASSES_C + tid];
        lg[tid] = s;
    }
    __syncthreads();

    if (tid == 0) {
        float m = lg[0];
        for (int cc = 1; cc < N_CLASSES_C; ++cc) m = fmaxf(m, lg[cc]);
        float s = 0.f;
        for (int cc = 0; cc < N_CLASSES_C; ++cc) s += expf(lg[cc] - m);
        lse = m + logf(s);
    }
    __syncthreads();

    if (tid < N_CLASSES_C)
        out[g * N_CLASSES_C + tid] = lg[tid] - lse;
}

// -------------------------------------------------------------------------
extern "C" void kernel_launch(void* const* d_in, const int* in_sizes, int n_in,
                              void* d_out, int out_size, void* d_ws, size_t ws_size,
                              hipStream_t stream)
{
    const float* x         = (const float*)d_in[0];
    const float* edge_attr = (const float*)d_in[1];
    const int*   ei        = (const int*)d_in[2];
    const int*   batch     = (const int*)d_in[3];
    const float* ee_w1     = (const float*)d_in[4];
    const float* ee_b1     = (const float*)d_in[5];
    const float* ee_w2     = (const float*)d_in[6];
    const float* ee_b2     = (const float*)d_in[7];
    const float* ee_bn_g   = (const float*)d_in[8];
    const float* ee_bn_b   = (const float*)d_in[9];
    const float* ee_bn_rm  = (const float*)d_in[10];
    const float* ee_bn_rv  = (const float*)d_in[11];
    const float* mlp_w1    = (const float*)d_in[12];
    const float* mlp_b1    = (const float*)d_in[13];
    const float* mlp_w2    = (const float*)d_in[14];
    const float* mlp_b2    = (const float*)d_in[15];
    const float* mlp_bn_g  = (const float*)d_in[16];
    const float* mlp_bn_b  = (const float*)d_in[17];
    const float* mlp_bn_rm = (const float*)d_in[18];
    const float* mlp_bn_rv = (const float*)d_in[19];
    const float* lin1_w    = (const float*)d_in[20];
    const float* lin1_b    = (const float*)d_in[21];
    const float* lin2_w    = (const float*)d_in[22];
    const float* lin2_b    = (const float*)d_in[23];
    float* out = (float*)d_out;

    const int* src = ei;
    const int* dst = ei + N_EDGES_C;

    // ---- workspace layout (bytes; ~119 MB) ----
    char* wsp = (char*)d_ws;
    float* x_cur = (float*)wsp;          wsp += (size_t)N_NODES_C * DIM_C * 4;
    float* agg   = (float*)wsp;          wsp += (size_t)N_NODES_C * DIM_C * 4;
    float* eaPerm = (float*)wsp;         wsp += (size_t)N_EDGES_C * EDGE_DIM_C * 4;
    unsigned short* emb = (unsigned short*)wsp; wsp += (size_t)CHUNK_C * DIM_C * 2;
    int* srcPerm = (int*)wsp;            wsp += (size_t)N_EDGES_C * 4;
    int* cnt     = (int*)wsp;            wsp += 200704;
    int* offsets = (int*)wsp;            wsp += 200704;
    int* cursor  = (int*)wsp;            wsp += 200704;
    float* sums  = (float*)wsp;          wsp += (size_t)N_GRAPHS_C * DIM_C * 4;
    float* cnts  = (float*)wsp;          wsp += 4096;
    short* W1T   = (short*)wsp;          wsp += (size_t)N_LAYERS_C * 128 * 16 * 2;
    short* W2T   = (short*)wsp;          wsp += (size_t)N_LAYERS_C * 128 * 128 * 2;
    short* MT1   = (short*)wsp;          wsp += (size_t)N_LAYERS_C * 128 * 128 * 2;
    short* MT2   = (short*)wsp;          wsp += (size_t)N_LAYERS_C * 128 * 128 * 2;

    // ---- preprocess: weight transpose + counting sort by dst ----
    wprep_kernel<<<12, 256, 0, stream>>>(ee_w1, ee_w2, mlp_w1, mlp_w2,
                                         W1T, W2T, MT1, MT2);
    hipMemsetAsync(cnt, 0, N_NODES_C * sizeof(int), stream);
    hist_kernel<<<(N_EDGES_C + 255) / 256, 256, 0, stream>>>(dst, cnt);
    scan_kernel<<<1, 1024, 0, stream>>>(cnt, offsets, cursor);
    scatter_kernel<<<(N_EDGES_C + 255) / 256, 256, 0, stream>>>(
        src, dst, edge_attr, cursor, srcPerm, eaPerm);

    const float* xin = x;
    for (int i = 0; i < N_LAYERS_C; ++i) {
        for (int c0 = 0; c0 < N_EDGES_C; c0 += CHUNK_C) {
            int c1 = min(c0 + CHUNK_C, N_EDGES_C);
            emb_mfma<<<256, 256, 0, stream>>>(
                eaPerm,
                W1T + (size_t)i * 128 * 16, ee_b1 + i * DIM_C,
                W2T + (size_t)i * 128 * 128, ee_b2 + i * DIM_C,
                ee_bn_g + i * DIM_C, ee_bn_b + i * DIM_C,
                ee_bn_rm + i * DIM_C, ee_bn_rv + i * DIM_C,
                emb, c0, c1 - c0);
            agg_kernel<<<(N_NODES_C + 7) / 8, 256, 0, stream>>>(
                emb, xin, srcPerm, offsets, agg, c0, c1, c0 == 0 ? 1 : 0);
        }
        node_mfma<<<256, 256, 0, stream>>>(
            xin, agg,
            MT1 + (size_t)i * 128 * 128, mlp_b1 + i * DIM_C,
            mlp_bn_g + i * DIM_C, mlp_bn_b + i * DIM_C,
            mlp_bn_rm + i * DIM_C, mlp_bn_rv + i * DIM_C,
            agg, N_NODES_C, 0);
        node_mfma<<<256, 256, 0, stream>>>(
            agg, nullptr,
            MT2 + (size_t)i * 128 * 128, mlp_b2 + i * DIM_C,
            mlp_bn_g + i * DIM_C, mlp_bn_b + i * DIM_C,
            mlp_bn_rm + i * DIM_C, mlp_bn_rv + i * DIM_C,
            x_cur, N_NODES_C, 1);
        xin = x_cur;
    }

    hipMemsetAsync(sums, 0,
                   ((size_t)N_GRAPHS_C * DIM_C + N_GRAPHS_C) * sizeof(float), stream);
    pool_kernel<<<1024, 256, 0, stream>>>(xin, batch, sums, cnts);
    head_kernel<<<N_GRAPHS_C, 128, 0, stream>>>(sums, cnts, lin1_w, lin1_b,
                                                lin2_w, lin2_b, out);
}

// Round 4
// 819.820 us; speedup vs baseline: 3.7342x; 1.1770x over previous
//
#include <hip/hip_runtime.h>

#define N_NODES_C 50000
#define N_EDGES_C 500000
#define EDGE_DIM_C 16
#define DIM_C 128
#define N_LAYERS_C 3
#define N_GRAPHS_C 512
#define N_CLASSES_C 10
#define BN_EPS_C 1e-5f

#define CHUNK_C 125000   // 4 chunk passes per layer; emb buf = 32 MB bf16
#define SCAN_NB ((N_NODES_C + 1023) / 1024)

typedef short bf16x8 __attribute__((ext_vector_type(8)));
typedef float f32x4  __attribute__((ext_vector_type(4)));

__device__ inline unsigned cvt_pk_bf16(float a, float b) {
    unsigned r;
    asm("v_cvt_pk_bf16_f32 %0, %1, %2" : "=v"(r) : "v"(a), "v"(b));
    return r;
}
__device__ inline float bf2f(unsigned short h) {
    union { unsigned u; float f; } v; v.u = ((unsigned)h) << 16;
    return v.f;
}
__device__ inline bf16x8 pack8(const float* f) {
    union { bf16x8 v; unsigned u[4]; } r;
    r.u[0] = cvt_pk_bf16(f[0], f[1]);
    r.u[1] = cvt_pk_bf16(f[2], f[3]);
    r.u[2] = cvt_pk_bf16(f[4], f[5]);
    r.u[3] = cvt_pk_bf16(f[6], f[7]);
    return r.v;
}

// -------------------------------------------------------------------------
// Preprocessing: counting sort of edges by dst (once per launch)
// -------------------------------------------------------------------------
__global__ void hist_kernel(const int* __restrict__ dst, int* __restrict__ cnt)
{
    int e = blockIdx.x * blockDim.x + threadIdx.x;
    if (e < N_EDGES_C) atomicAdd(&cnt[dst[e]], 1);
}

// 3-phase multi-block scan
__global__ __launch_bounds__(1024)
void scan1_kernel(const int* __restrict__ cnt, int* __restrict__ incl,
                  int* __restrict__ bsum)
{
    __shared__ int buf[1024];
    int i = blockIdx.x * 1024 + threadIdx.x;
    int v = (i < N_NODES_C) ? cnt[i] : 0;
    buf[threadIdx.x] = v;
    __syncthreads();
    for (int off = 1; off < 1024; off <<= 1) {
        int t = (threadIdx.x >= off) ? buf[threadIdx.x - off] : 0;
        __syncthreads();
        buf[threadIdx.x] += t;
        __syncthreads();
    }
    if (i < N_NODES_C) incl[i] = buf[threadIdx.x];
    if (threadIdx.x == 1023) bsum[blockIdx.x] = buf[1023];
}

__global__ void scan2_kernel(int* __restrict__ bsum)
{
    if (threadIdx.x == 0 && blockIdx.x == 0) {
        int run = 0;
        for (int b = 0; b < SCAN_NB; ++b) { int v = bsum[b]; bsum[b] = run; run += v; }
    }
}

__global__ __launch_bounds__(1024)
void scan3_kernel(const int* __restrict__ cnt, const int* __restrict__ incl,
                  const int* __restrict__ bsum,
                  int* __restrict__ offsets, int* __restrict__ cursor)
{
    int i = blockIdx.x * 1024 + threadIdx.x;
    if (i < N_NODES_C) {
        int inc = incl[i] + bsum[blockIdx.x];
        offsets[i + 1] = inc;
        cursor[i] = inc - cnt[i];
        if (i == 0) offsets[0] = 0;
    }
}

__global__ void scatter_kernel(const int* __restrict__ src,
                               const int* __restrict__ dst,
                               const float* __restrict__ ea,
                               int* __restrict__ cursor,
                               int* __restrict__ srcPerm,
                               float* __restrict__ eaPerm)
{
    int e = blockIdx.x * blockDim.x + threadIdx.x;
    if (e >= N_EDGES_C) return;
    int pos = atomicAdd(&cursor[dst[e]], 1);
    srcPerm[pos] = src[e];
    const float4* in = (const float4*)&ea[(size_t)e * EDGE_DIM_C];
    float4* out = (float4*)&eaPerm[(size_t)pos * EDGE_DIM_C];
    out[0] = in[0]; out[1] = in[1]; out[2] = in[2]; out[3] = in[3];
}

// graph boundaries: goff[g] = lower_bound(batch, g); batch is sorted
__global__ __launch_bounds__(512)
void goff_kernel(const int* __restrict__ batch, int* __restrict__ goff)
{
    int g = threadIdx.x;
    int lo = 0, hi = N_NODES_C;
    while (lo < hi) {
        int mid = (lo + hi) >> 1;
        if (batch[mid] < g) lo = mid + 1; else hi = mid;
    }
    goff[g] = lo;
    if (g == 0) goff[N_GRAPHS_C] = N_NODES_C;
}

// -------------------------------------------------------------------------
// Weight prep: transpose + bf16-convert all GEMM weights once per launch.
// -------------------------------------------------------------------------
__global__ __launch_bounds__(256)
void wprep_kernel(const float* __restrict__ ee_w1, const float* __restrict__ ee_w2,
                  const float* __restrict__ mlp_w1, const float* __restrict__ mlp_w2,
                  short* __restrict__ W1T, short* __restrict__ W2T,
                  short* __restrict__ MT1, short* __restrict__ MT2)
{
    int b = blockIdx.x;
    int l = b % 3;
    int which = b / 3;
    if (which == 0) {
        const float* in = ee_w1 + l * 16 * 128;
        short* outp = W1T + l * 128 * 16;
        for (int i = threadIdx.x; i < 2048; i += 256) {
            int f = i >> 4, k = i & 15;
            outp[i] = (short)(cvt_pk_bf16(in[k * 128 + f], 0.f) & 0xffff);
        }
    } else {
        const float* in = (which == 1 ? ee_w2 : which == 2 ? mlp_w1 : mlp_w2) + l * 128 * 128;
        short* outp = (which == 1 ? W2T : which == 2 ? MT1 : MT2) + l * 128 * 128;
        for (int i = threadIdx.x; i < 16384; i += 256) {
            int f = i >> 7, k = i & 127;
            outp[i] = (short)(cvt_pk_bf16(in[k * 128 + f], 0.f) & 0xffff);
        }
    }
}

// -------------------------------------------------------------------------
// MFMA edge-encoder (unchanged from round 3)
// -------------------------------------------------------------------------
__global__ __launch_bounds__(256)
void emb_mfma(const float* __restrict__ eaPerm,
              const short* __restrict__ W1T, const float* __restrict__ b1,
              const short* __restrict__ W2T, const float* __restrict__ b2,
              const float* __restrict__ bng, const float* __restrict__ bnb,
              const float* __restrict__ bnrm, const float* __restrict__ bnrv,
              unsigned short* __restrict__ emb, int c0, int chunkN)
{
    __shared__ short t1s[2][64 * 128];

    const int tid  = threadIdx.x;
    const int lane = tid & 63;
    const int w    = tid >> 6;
    const int et   = w >> 1;
    const int cg   = w & 1;
    const int ln15 = lane & 15;
    const int g    = lane >> 4;
    const int colbase = cg * 64;

    bf16x8 fw1[4], fw2[4][4];
    #pragma unroll
    for (int ct = 0; ct < 4; ++ct) {
        int f = colbase + ct * 16 + ln15;
        if (g < 2) fw1[ct] = *(const bf16x8*)&W1T[f * 16 + g * 8];
        else       fw1[ct] = (bf16x8){0,0,0,0,0,0,0,0};
        #pragma unroll
        for (int kb = 0; kb < 4; ++kb)
            fw2[ct][kb] = *(const bf16x8*)&W2T[f * 128 + kb * 32 + g * 8];
    }
    float b1v[4], b2v[4], scv[4], shv[4];
    #pragma unroll
    for (int ct = 0; ct < 4; ++ct) {
        int f = colbase + ct * 16 + ln15;
        b1v[ct] = b1[f]; b2v[ct] = b2[f];
        float sc = bng[f] * rsqrtf(bnrv[f] + BN_EPS_C);
        scv[ct] = sc; shv[ct] = bnb[f] - bnrm[f] * sc;
    }

    const int niter = (chunkN + 127) / 128;
    for (int it = blockIdx.x; it < niter; it += gridDim.x) {
        const int eb = it * 128 + et * 64;

        #pragma unroll
        for (int rt = 0; rt < 4; ++rt) {
            bf16x8 af;
            if (g < 2) {
                int erow = min(eb + rt * 16 + ln15, chunkN - 1);
                const float* p = &eaPerm[(size_t)(c0 + erow) * 16 + g * 8];
                float fv[8];
                *(float4*)&fv[0] = *(const float4*)p;
                *(float4*)&fv[4] = *(const float4*)(p + 4);
                af = pack8(fv);
            } else {
                af = (bf16x8){0,0,0,0,0,0,0,0};
            }
            #pragma unroll
            for (int ct = 0; ct < 4; ++ct) {
                f32x4 a1 = { b1v[ct], b1v[ct], b1v[ct], b1v[ct] };
                a1 = __builtin_amdgcn_mfma_f32_16x16x32_bf16(af, fw1[ct], a1, 0, 0, 0);
                int col = colbase + ct * 16 + ln15;
                #pragma unroll
                for (int r = 0; r < 4; ++r) {
                    int row = rt * 16 + g * 4 + r;
                    int idx = (row * 128 + col) ^ ((row & 15) << 3);
                    t1s[et][idx] = (short)(cvt_pk_bf16(fmaxf(a1[r], 0.f), 0.f) & 0xffff);
                }
            }
        }
        __syncthreads();

        f32x4 acc[4][4];
        #pragma unroll
        for (int rt = 0; rt < 4; ++rt)
            #pragma unroll
            for (int ct = 0; ct < 4; ++ct)
                acc[rt][ct] = (f32x4){ b2v[ct], b2v[ct], b2v[ct], b2v[ct] };

        #pragma unroll
        for (int rt = 0; rt < 4; ++rt) {
            bf16x8 a[4];
            int row = rt * 16 + ln15;
            #pragma unroll
            for (int kb = 0; kb < 4; ++kb) {
                int idx = (row * 128 + kb * 32 + g * 8) ^ ((row & 15) << 3);
                a[kb] = *(const bf16x8*)&t1s[et][idx];
            }
            #pragma unroll
            for (int ct = 0; ct < 4; ++ct)
                #pragma unroll
                for (int kb = 0; kb < 4; ++kb)
                    acc[rt][ct] = __builtin_amdgcn_mfma_f32_16x16x32_bf16(
                        a[kb], fw2[ct][kb], acc[rt][ct], 0, 0, 0);
        }

        #pragma unroll
        for (int rt = 0; rt < 4; ++rt)
            #pragma unroll
            for (int ct = 0; ct < 4; ++ct) {
                int col = colbase + ct * 16 + ln15;
                #pragma unroll
                for (int r = 0; r < 4; ++r) {
                    int row = eb + rt * 16 + g * 4 + r;
                    if (row < chunkN) {
                        float v = fmaxf(acc[rt][ct][r], 0.f) * scv[ct] + shv[ct];
                        emb[(size_t)row * 128 + col] =
                            (unsigned short)(cvt_pk_bf16(v, 0.f) & 0xffff);
                    }
                }
            }
        __syncthreads();
    }
}

// -------------------------------------------------------------------------
// MFMA node MLP (unchanged from round 3)
// -------------------------------------------------------------------------
__global__ __launch_bounds__(256)
void node_mfma(const float* __restrict__ in0, const float* __restrict__ in1,
               const short* __restrict__ WT, const float* __restrict__ bias,
               const float* __restrict__ bng, const float* __restrict__ bnb,
               const float* __restrict__ bnrm, const float* __restrict__ bnrv,
               float* __restrict__ out, int nrows, int use_bn)
{
    __shared__ short hs[2][64 * 128];

    const int tid  = threadIdx.x;
    const int lane = tid & 63;
    const int w    = tid >> 6;
    const int et   = w >> 1;
    const int cg   = w & 1;
    const int ln15 = lane & 15;
    const int g    = lane >> 4;
    const int colbase = cg * 64;

    bf16x8 fw[4][4];
    float bv[4], scv[4], shv[4];
    #pragma unroll
    for (int ct = 0; ct < 4; ++ct) {
        int f = colbase + ct * 16 + ln15;
        #pragma unroll
        for (int kb = 0; kb < 4; ++kb)
            fw[ct][kb] = *(const bf16x8*)&WT[f * 128 + kb * 32 + g * 8];
        bv[ct] = bias[f];
        if (use_bn) {
            float sc = bng[f] * rsqrtf(bnrv[f] + BN_EPS_C);
            scv[ct] = sc; shv[ct] = bnb[f] - bnrm[f] * sc;
        } else { scv[ct] = 1.f; shv[ct] = 0.f; }
    }

    const int niter = (nrows + 127) / 128;
    for (int it = blockIdx.x; it < niter; it += gridDim.x) {
        const int base = it * 128;

        for (int i = tid; i < 4096; i += 256) {
            int row = i >> 5;
            int c4  = (i & 31) * 4;
            int rr  = min(base + row, nrows - 1);
            float4 v = *(const float4*)&in0[(size_t)rr * 128 + c4];
            if (in1) {
                float4 a1 = *(const float4*)&in1[(size_t)rr * 128 + c4];
                v.x += a1.x; v.y += a1.y; v.z += a1.z; v.w += a1.w;
            }
            int e = row >> 6, r = row & 63;
            int idx = (r * 128 + c4) ^ ((r & 15) << 3);
            *(unsigned*)&hs[e][idx]     = cvt_pk_bf16(v.x, v.y);
            *(unsigned*)&hs[e][idx + 2] = cvt_pk_bf16(v.z, v.w);
        }
        __syncthreads();

        f32x4 acc[4][4];
        #pragma unroll
        for (int rt = 0; rt < 4; ++rt)
            #pragma unroll
            for (int ct = 0; ct < 4; ++ct)
                acc[rt][ct] = (f32x4){ bv[ct], bv[ct], bv[ct], bv[ct] };

        #pragma unroll
        for (int rt = 0; rt < 4; ++rt) {
            bf16x8 a[4];
            int row = rt * 16 + ln15;
            #pragma unroll
            for (int kb = 0; kb < 4; ++kb) {
                int idx = (row * 128 + kb * 32 + g * 8) ^ ((row & 15) << 3);
                a[kb] = *(const bf16x8*)&hs[et][idx];
            }
            #pragma unroll
            for (int ct = 0; ct < 4; ++ct)
                #pragma unroll
                for (int kb = 0; kb < 4; ++kb)
                    acc[rt][ct] = __builtin_amdgcn_mfma_f32_16x16x32_bf16(
                        a[kb], fw[ct][kb], acc[rt][ct], 0, 0, 0);
        }

        #pragma unroll
        for (int rt = 0; rt < 4; ++rt)
            #pragma unroll
            for (int ct = 0; ct < 4; ++ct) {
                int col = colbase + ct * 16 + ln15;
                #pragma unroll
                for (int r = 0; r < 4; ++r) {
                    int row = base + et * 64 + rt * 16 + g * 4 + r;
                    if (row < nrows) {
                        float v = fmaxf(acc[rt][ct][r], 0.f) * scv[ct] + shv[ct];
                        out[(size_t)row * 128 + col] = v;
                    }
                }
            }
        __syncthreads();
    }
}

// -------------------------------------------------------------------------
// CSR aggregation (atomic-free): 32 lanes per node, 8 nodes per block.
// -------------------------------------------------------------------------
__global__ __launch_bounds__(256)
void agg_kernel(const unsigned short* __restrict__ emb,
                const float* __restrict__ x,
                const int* __restrict__ srcPerm,
                const int* __restrict__ offsets,
                float* __restrict__ agg,
                int c0, int c1, int first)
{
    const int slot = threadIdx.x >> 5;
    const int l    = threadIdx.x & 31;
    const int n = blockIdx.x * 8 + slot;
    if (n >= N_NODES_C) return;

    int lo = offsets[n], hi = offsets[n + 1];
    lo = max(lo, c0); hi = min(hi, c1);

    float4 s = make_float4(0.f, 0.f, 0.f, 0.f);
    const bool any = lo < hi;
    for (int pos = lo; pos < hi; ++pos) {
        int srcn = srcPerm[pos];
        ushort4 eb = *(const ushort4*)&emb[(size_t)(pos - c0) * DIM_C + l * 4];
        float4 xv = *(const float4*)&x[(size_t)srcn * DIM_C + l * 4];
        s.x += fmaxf(xv.x + bf2f(eb.x), 0.f);
        s.y += fmaxf(xv.y + bf2f(eb.y), 0.f);
        s.z += fmaxf(xv.z + bf2f(eb.z), 0.f);
        s.w += fmaxf(xv.w + bf2f(eb.w), 0.f);
    }

    float4* ap = (float4*)&agg[(size_t)n * DIM_C + l * 4];
    if (first) {
        *ap = s;
    } else if (any) {
        float4 o = *ap;
        o.x += s.x; o.y += s.y; o.z += s.z; o.w += s.w;
        *ap = o;
    }
}

// -------------------------------------------------------------------------
// Segmented mean pool (atomic-free): one block per graph, batch is sorted.
// -------------------------------------------------------------------------
__global__ __launch_bounds__(128)
void pool2_kernel(const float* __restrict__ x,
                  const int* __restrict__ goff,
                  float* __restrict__ pooled)
{
    const int g = blockIdx.x;
    const int tid = threadIdx.x;
    int lo = goff[g], hi = goff[g + 1];
    float s = 0.f;
    for (int n = lo; n < hi; ++n)
        s += x[(size_t)n * DIM_C + tid];
    float c = (float)max(hi - lo, 1);
    pooled[g * DIM_C + tid] = s / c;
}

// -------------------------------------------------------------------------
// Readout head: pooled -> relu(lin1) -> lin2 -> log_softmax.
// -------------------------------------------------------------------------
__global__ __launch_bounds__(128)
void head_kernel(const float* __restrict__ pooled,
                 const float* __restrict__ l1w,
                 const float* __restrict__ l1b,
                 const float* __restrict__ l2w,
                 const float* __restrict__ l2b,
                 float* __restrict__ out)
{
    const int g = blockIdx.x;
    const int tid = threadIdx.x;
    __shared__ float ps[DIM_C];
    __shared__ float hsx[DIM_C];
    __shared__ float lg[N_CLASSES_C];
    __shared__ float lse;

    ps[tid] = pooled[g * DIM_C + tid];
    __syncthreads();

    float a = l1b[tid];
    for (int k = 0; k < DIM_C; ++k)
        a += ps[k] * l1w[k * DIM_C + tid];
    hsx[tid] = fmaxf(a, 0.f);
    __syncthreads();

    if (tid < N_CLASSES_C) {
        float s = l2b[tid];
        for (int f = 0; f < DIM_C; ++f)
            s += hsx[f] * l2w[f * N_CLASSES_C + tid];
        lg[tid] = s;
    }
    __syncthreads();

    if (tid == 0) {
        float m = lg[0];
        for (int cc = 1; cc < N_CLASSES_C; ++cc) m = fmaxf(m, lg[cc]);
        float s = 0.f;
        for (int cc = 0; cc < N_CLASSES_C; ++cc) s += expf(lg[cc] - m);
        lse = m + logf(s);
    }
    __syncthreads();

    if (tid < N_CLASSES_C)
        out[g * N_CLASSES_C + tid] = lg[tid] - lse;
}

// -------------------------------------------------------------------------
extern "C" void kernel_launch(void* const* d_in, const int* in_sizes, int n_in,
                              void* d_out, int out_size, void* d_ws, size_t ws_size,
                              hipStream_t stream)
{
    const float* x         = (const float*)d_in[0];
    const float* edge_attr = (const float*)d_in[1];
    const int*   ei        = (const int*)d_in[2];
    const int*   batch     = (const int*)d_in[3];
    const float* ee_w1     = (const float*)d_in[4];
    const float* ee_b1     = (const float*)d_in[5];
    const float* ee_w2     = (const float*)d_in[6];
    const float* ee_b2     = (const float*)d_in[7];
    const float* ee_bn_g   = (const float*)d_in[8];
    const float* ee_bn_b   = (const float*)d_in[9];
    const float* ee_bn_rm  = (const float*)d_in[10];
    const float* ee_bn_rv  = (const float*)d_in[11];
    const float* mlp_w1    = (const float*)d_in[12];
    const float* mlp_b1    = (const float*)d_in[13];
    const float* mlp_w2    = (const float*)d_in[14];
    const float* mlp_b2    = (const float*)d_in[15];
    const float* mlp_bn_g  = (const float*)d_in[16];
    const float* mlp_bn_b  = (const float*)d_in[17];
    const float* mlp_bn_rm = (const float*)d_in[18];
    const float* mlp_bn_rv = (const float*)d_in[19];
    const float* lin1_w    = (const float*)d_in[20];
    const float* lin1_b    = (const float*)d_in[21];
    const float* lin2_w    = (const float*)d_in[22];
    const float* lin2_b    = (const float*)d_in[23];
    float* out = (float*)d_out;

    const int* src = ei;
    const int* dst = ei + N_EDGES_C;

    // ---- workspace layout (bytes; ~120 MB) ----
    char* wsp = (char*)d_ws;
    float* x_cur = (float*)wsp;          wsp += (size_t)N_NODES_C * DIM_C * 4;
    float* agg   = (float*)wsp;          wsp += (size_t)N_NODES_C * DIM_C * 4;
    float* eaPerm = (float*)wsp;         wsp += (size_t)N_EDGES_C * EDGE_DIM_C * 4;
    unsigned short* emb = (unsigned short*)wsp; wsp += (size_t)CHUNK_C * DIM_C * 2;
    int* srcPerm = (int*)wsp;            wsp += (size_t)N_EDGES_C * 4;
    int* cnt     = (int*)wsp;            wsp += 200704;
    int* offsets = (int*)wsp;            wsp += 200704;
    int* cursor  = (int*)wsp;            wsp += 200704;
    int* incl    = (int*)wsp;            wsp += 200704;
    int* bsum    = (int*)wsp;            wsp += 4096;
    int* goff    = (int*)wsp;            wsp += 4096;
    float* pooled = (float*)wsp;         wsp += (size_t)N_GRAPHS_C * DIM_C * 4;
    short* W1T   = (short*)wsp;          wsp += (size_t)N_LAYERS_C * 128 * 16 * 2;
    short* W2T   = (short*)wsp;          wsp += (size_t)N_LAYERS_C * 128 * 128 * 2;
    short* MT1   = (short*)wsp;          wsp += (size_t)N_LAYERS_C * 128 * 128 * 2;
    short* MT2   = (short*)wsp;          wsp += (size_t)N_LAYERS_C * 128 * 128 * 2;

    // ---- preprocess: weight transpose + counting sort + graph bounds ----
    wprep_kernel<<<12, 256, 0, stream>>>(ee_w1, ee_w2, mlp_w1, mlp_w2,
                                         W1T, W2T, MT1, MT2);
    hipMemsetAsync(cnt, 0, N_NODES_C * sizeof(int), stream);
    hist_kernel<<<(N_EDGES_C + 255) / 256, 256, 0, stream>>>(dst, cnt);
    scan1_kernel<<<SCAN_NB, 1024, 0, stream>>>(cnt, incl, bsum);
    scan2_kernel<<<1, 64, 0, stream>>>(bsum);
    scan3_kernel<<<SCAN_NB, 1024, 0, stream>>>(cnt, incl, bsum, offsets, cursor);
    scatter_kernel<<<(N_EDGES_C + 255) / 256, 256, 0, stream>>>(
        src, dst, edge_attr, cursor, srcPerm, eaPerm);
    goff_kernel<<<1, 512, 0, stream>>>(batch, goff);

    const float* xin = x;
    for (int i = 0; i < N_LAYERS_C; ++i) {
        for (int c0 = 0; c0 < N_EDGES_C; c0 += CHUNK_C) {
            int c1 = min(c0 + CHUNK_C, N_EDGES_C);
            emb_mfma<<<256, 256, 0, stream>>>(
                eaPerm,
                W1T + (size_t)i * 128 * 16, ee_b1 + i * DIM_C,
                W2T + (size_t)i * 128 * 128, ee_b2 + i * DIM_C,
                ee_bn_g + i * DIM_C, ee_bn_b + i * DIM_C,
                ee_bn_rm + i * DIM_C, ee_bn_rv + i * DIM_C,
                emb, c0, c1 - c0);
            agg_kernel<<<(N_NODES_C + 7) / 8, 256, 0, stream>>>(
                emb, xin, srcPerm, offsets, agg, c0, c1, c0 == 0 ? 1 : 0);
        }
        node_mfma<<<256, 256, 0, stream>>>(
            xin, agg,
            MT1 + (size_t)i * 128 * 128, mlp_b1 + i * DIM_C,
            mlp_bn_g + i * DIM_C, mlp_bn_b + i * DIM_C,
            mlp_bn_rm + i * DIM_C, mlp_bn_rv + i * DIM_C,
            agg, N_NODES_C, 0);
        node_mfma<<<256, 256, 0, stream>>>(
            agg, nullptr,
            MT2 + (size_t)i * 128 * 128, mlp_b2 + i * DIM_C,
            mlp_bn_g + i * DIM_C, mlp_bn_b + i * DIM_C,
            mlp_bn_rm + i * DIM_C, mlp_bn_rv + i * DIM_C,
            x_cur, N_NODES_C, 1);
        xin = x_cur;
    }

    pool2_kernel<<<N_GRAPHS_C, 128, 0, stream>>>(xin, goff, pooled);
    head_kernel<<<N_GRAPHS_C, 128, 0, stream>>>(pooled, lin1_w, lin1_b,
                                                lin2_w, lin2_b, out);
}

// Round 5
// 686.257 us; speedup vs baseline: 4.4610x; 1.1946x over previous
//
#include <hip/hip_runtime.h>

#define N_NODES_C 50000
#define N_EDGES_C 500000
#define EDGE_DIM_C 16
#define DIM_C 128
#define N_LAYERS_C 3
#define N_GRAPHS_C 512
#define N_CLASSES_C 10
#define BN_EPS_C 1e-5f

#define SCAN_NB ((N_NODES_C + 1023) / 1024)

typedef short bf16x8 __attribute__((ext_vector_type(8)));
typedef float f32x4  __attribute__((ext_vector_type(4)));

__device__ inline unsigned cvt_pk_bf16(float a, float b) {
    unsigned r;
    asm("v_cvt_pk_bf16_f32 %0, %1, %2" : "=v"(r) : "v"(a), "v"(b));
    return r;
}
__device__ inline float bf2f(unsigned short h) {
    union { unsigned u; float f; } v; v.u = ((unsigned)h) << 16;
    return v.f;
}

// -------------------------------------------------------------------------
// Preprocessing: counting sort of edges by dst (once per launch)
// -------------------------------------------------------------------------
__global__ void hist_kernel(const int* __restrict__ dst, int* __restrict__ cnt)
{
    int e = blockIdx.x * blockDim.x + threadIdx.x;
    if (e < N_EDGES_C) atomicAdd(&cnt[dst[e]], 1);
}

// 3-phase multi-block scan
__global__ __launch_bounds__(1024)
void scan1_kernel(const int* __restrict__ cnt, int* __restrict__ incl,
                  int* __restrict__ bsum)
{
    __shared__ int buf[1024];
    int i = blockIdx.x * 1024 + threadIdx.x;
    int v = (i < N_NODES_C) ? cnt[i] : 0;
    buf[threadIdx.x] = v;
    __syncthreads();
    for (int off = 1; off < 1024; off <<= 1) {
        int t = (threadIdx.x >= off) ? buf[threadIdx.x - off] : 0;
        __syncthreads();
        buf[threadIdx.x] += t;
        __syncthreads();
    }
    if (i < N_NODES_C) incl[i] = buf[threadIdx.x];
    if (threadIdx.x == 1023) bsum[blockIdx.x] = buf[1023];
}

__global__ void scan2_kernel(int* __restrict__ bsum)
{
    if (threadIdx.x == 0 && blockIdx.x == 0) {
        int run = 0;
        for (int b = 0; b < SCAN_NB; ++b) { int v = bsum[b]; bsum[b] = run; run += v; }
    }
}

__global__ __launch_bounds__(1024)
void scan3_kernel(const int* __restrict__ cnt, const int* __restrict__ incl,
                  const int* __restrict__ bsum,
                  int* __restrict__ offsets, int* __restrict__ cursor)
{
    int i = blockIdx.x * 1024 + threadIdx.x;
    if (i < N_NODES_C) {
        int inc = incl[i] + bsum[blockIdx.x];
        offsets[i + 1] = inc;
        cursor[i] = inc - cnt[i];
        if (i == 0) offsets[0] = 0;
    }
}

// permute edges by dst; edge_attr converted to bf16 (32 B/edge random write)
__global__ void scatter_kernel(const int* __restrict__ src,
                               const int* __restrict__ dst,
                               const float* __restrict__ ea,
                               int* __restrict__ cursor,
                               int* __restrict__ srcPerm,
                               unsigned short* __restrict__ eaPermH)
{
    int e = blockIdx.x * blockDim.x + threadIdx.x;
    if (e >= N_EDGES_C) return;
    int pos = atomicAdd(&cursor[dst[e]], 1);
    srcPerm[pos] = src[e];
    const float4* in = (const float4*)&ea[(size_t)e * EDGE_DIM_C];
    float4 a = in[0], b = in[1], c = in[2], d = in[3];
    uint4 lo, hi;
    lo.x = cvt_pk_bf16(a.x, a.y); lo.y = cvt_pk_bf16(a.z, a.w);
    lo.z = cvt_pk_bf16(b.x, b.y); lo.w = cvt_pk_bf16(b.z, b.w);
    hi.x = cvt_pk_bf16(c.x, c.y); hi.y = cvt_pk_bf16(c.z, c.w);
    hi.z = cvt_pk_bf16(d.x, d.y); hi.w = cvt_pk_bf16(d.z, d.w);
    uint4* outp = (uint4*)&eaPermH[(size_t)pos * EDGE_DIM_C];
    outp[0] = lo; outp[1] = hi;
}

// graph boundaries: goff[g] = lower_bound(batch, g); batch is sorted
__global__ __launch_bounds__(512)
void goff_kernel(const int* __restrict__ batch, int* __restrict__ goff)
{
    int g = threadIdx.x;
    int lo = 0, hi = N_NODES_C;
    while (lo < hi) {
        int mid = (lo + hi) >> 1;
        if (batch[mid] < g) lo = mid + 1; else hi = mid;
    }
    goff[g] = lo;
    if (g == 0) goff[N_GRAPHS_C] = N_NODES_C;
}

// -------------------------------------------------------------------------
// Weight prep: transpose + bf16-convert all GEMM weights once per launch.
// -------------------------------------------------------------------------
__global__ __launch_bounds__(256)
void wprep_kernel(const float* __restrict__ ee_w1, const float* __restrict__ ee_w2,
                  const float* __restrict__ mlp_w1, const float* __restrict__ mlp_w2,
                  short* __restrict__ W1T, short* __restrict__ W2T,
                  short* __restrict__ MT1, short* __restrict__ MT2)
{
    int b = blockIdx.x;
    int l = b % 3;
    int which = b / 3;
    if (which == 0) {
        const float* in = ee_w1 + l * 16 * 128;
        short* outp = W1T + l * 128 * 16;
        for (int i = threadIdx.x; i < 2048; i += 256) {
            int f = i >> 4, k = i & 15;
            outp[i] = (short)(cvt_pk_bf16(in[k * 128 + f], 0.f) & 0xffff);
        }
    } else {
        const float* in = (which == 1 ? ee_w2 : which == 2 ? mlp_w1 : mlp_w2) + l * 128 * 128;
        short* outp = (which == 1 ? W2T : which == 2 ? MT1 : MT2) + l * 128 * 128;
        for (int i = threadIdx.x; i < 16384; i += 256) {
            int f = i >> 7, k = i & 127;
            outp[i] = (short)(cvt_pk_bf16(in[k * 128 + f], 0.f) & 0xffff);
        }
    }
}

// -------------------------------------------------------------------------
// MFMA edge-encoder: stage1 reads bf16 eaPermH fragments directly.
// -------------------------------------------------------------------------
__global__ __launch_bounds__(256)
void emb_mfma(const unsigned short* __restrict__ eaPermH,
              const short* __restrict__ W1T, const float* __restrict__ b1,
              const short* __restrict__ W2T, const float* __restrict__ b2,
              const float* __restrict__ bng, const float* __restrict__ bnb,
              const float* __restrict__ bnrm, const float* __restrict__ bnrv,
              unsigned short* __restrict__ emb, int c0, int chunkN)
{
    __shared__ short t1s[2][64 * 128];

    const int tid  = threadIdx.x;
    const int lane = tid & 63;
    const int w    = tid >> 6;
    const int et   = w >> 1;
    const int cg   = w & 1;
    const int ln15 = lane & 15;
    const int g    = lane >> 4;
    const int colbase = cg * 64;

    bf16x8 fw1[4], fw2[4][4];
    #pragma unroll
    for (int ct = 0; ct < 4; ++ct) {
        int f = colbase + ct * 16 + ln15;
        if (g < 2) fw1[ct] = *(const bf16x8*)&W1T[f * 16 + g * 8];
        else       fw1[ct] = (bf16x8){0,0,0,0,0,0,0,0};
        #pragma unroll
        for (int kb = 0; kb < 4; ++kb)
            fw2[ct][kb] = *(const bf16x8*)&W2T[f * 128 + kb * 32 + g * 8];
    }
    float b1v[4], b2v[4], scv[4], shv[4];
    #pragma unroll
    for (int ct = 0; ct < 4; ++ct) {
        int f = colbase + ct * 16 + ln15;
        b1v[ct] = b1[f]; b2v[ct] = b2[f];
        float sc = bng[f] * rsqrtf(bnrv[f] + BN_EPS_C);
        scv[ct] = sc; shv[ct] = bnb[f] - bnrm[f] * sc;
    }

    const int niter = (chunkN + 127) / 128;
    for (int it = blockIdx.x; it < niter; it += gridDim.x) {
        const int eb = it * 128 + et * 64;

        #pragma unroll
        for (int rt = 0; rt < 4; ++rt) {
            bf16x8 af;
            if (g < 2) {
                int erow = min(eb + rt * 16 + ln15, chunkN - 1);
                af = *(const bf16x8*)&eaPermH[(size_t)(c0 + erow) * EDGE_DIM_C + g * 8];
            } else {
                af = (bf16x8){0,0,0,0,0,0,0,0};
            }
            #pragma unroll
            for (int ct = 0; ct < 4; ++ct) {
                f32x4 a1 = { b1v[ct], b1v[ct], b1v[ct], b1v[ct] };
                a1 = __builtin_amdgcn_mfma_f32_16x16x32_bf16(af, fw1[ct], a1, 0, 0, 0);
                int col = colbase + ct * 16 + ln15;
                #pragma unroll
                for (int r = 0; r < 4; ++r) {
                    int row = rt * 16 + g * 4 + r;
                    int idx = (row * 128 + col) ^ ((row & 15) << 3);
                    t1s[et][idx] = (short)(cvt_pk_bf16(fmaxf(a1[r], 0.f), 0.f) & 0xffff);
                }
            }
        }
        __syncthreads();

        f32x4 acc[4][4];
        #pragma unroll
        for (int rt = 0; rt < 4; ++rt)
            #pragma unroll
            for (int ct = 0; ct < 4; ++ct)
                acc[rt][ct] = (f32x4){ b2v[ct], b2v[ct], b2v[ct], b2v[ct] };

        #pragma unroll
        for (int rt = 0; rt < 4; ++rt) {
            bf16x8 a[4];
            int row = rt * 16 + ln15;
            #pragma unroll
            for (int kb = 0; kb < 4; ++kb) {
                int idx = (row * 128 + kb * 32 + g * 8) ^ ((row & 15) << 3);
                a[kb] = *(const bf16x8*)&t1s[et][idx];
            }
            #pragma unroll
            for (int ct = 0; ct < 4; ++ct)
                #pragma unroll
                for (int kb = 0; kb < 4; ++kb)
                    acc[rt][ct] = __builtin_amdgcn_mfma_f32_16x16x32_bf16(
                        a[kb], fw2[ct][kb], acc[rt][ct], 0, 0, 0);
        }

        #pragma unroll
        for (int rt = 0; rt < 4; ++rt)
            #pragma unroll
            for (int ct = 0; ct < 4; ++ct) {
                int col = colbase + ct * 16 + ln15;
                #pragma unroll
                for (int r = 0; r < 4; ++r) {
                    int row = eb + rt * 16 + g * 4 + r;
                    if (row < chunkN) {
                        float v = fmaxf(acc[rt][ct][r], 0.f) * scv[ct] + shv[ct];
                        emb[(size_t)row * 128 + col] =
                            (unsigned short)(cvt_pk_bf16(v, 0.f) & 0xffff);
                    }
                }
            }
        __syncthreads();
    }
}

// -------------------------------------------------------------------------
// MFMA node MLP (unchanged)
// -------------------------------------------------------------------------
__global__ __launch_bounds__(256)
void node_mfma(const float* __restrict__ in0, const float* __restrict__ in1,
               const short* __restrict__ WT, const float* __restrict__ bias,
               const float* __restrict__ bng, const float* __restrict__ bnb,
               const float* __restrict__ bnrm, const float* __restrict__ bnrv,
               float* __restrict__ out, int nrows, int use_bn)
{
    __shared__ short hs[2][64 * 128];

    const int tid  = threadIdx.x;
    const int lane = tid & 63;
    const int w    = tid >> 6;
    const int et   = w >> 1;
    const int cg   = w & 1;
    const int ln15 = lane & 15;
    const int g    = lane >> 4;
    const int colbase = cg * 64;

    bf16x8 fw[4][4];
    float bv[4], scv[4], shv[4];
    #pragma unroll
    for (int ct = 0; ct < 4; ++ct) {
        int f = colbase + ct * 16 + ln15;
        #pragma unroll
        for (int kb = 0; kb < 4; ++kb)
            fw[ct][kb] = *(const bf16x8*)&WT[f * 128 + kb * 32 + g * 8];
        bv[ct] = bias[f];
        if (use_bn) {
            float sc = bng[f] * rsqrtf(bnrv[f] + BN_EPS_C);
            scv[ct] = sc; shv[ct] = bnb[f] - bnrm[f] * sc;
        } else { scv[ct] = 1.f; shv[ct] = 0.f; }
    }

    const int niter = (nrows + 127) / 128;
    for (int it = blockIdx.x; it < niter; it += gridDim.x) {
        const int base = it * 128;

        for (int i = tid; i < 4096; i += 256) {
            int row = i >> 5;
            int c4  = (i & 31) * 4;
            int rr  = min(base + row, nrows - 1);
            float4 v = *(const float4*)&in0[(size_t)rr * 128 + c4];
            if (in1) {
                float4 a1 = *(const float4*)&in1[(size_t)rr * 128 + c4];
                v.x += a1.x; v.y += a1.y; v.z += a1.z; v.w += a1.w;
            }
            int e = row >> 6, r = row & 63;
            int idx = (r * 128 + c4) ^ ((r & 15) << 3);
            *(unsigned*)&hs[e][idx]     = cvt_pk_bf16(v.x, v.y);
            *(unsigned*)&hs[e][idx + 2] = cvt_pk_bf16(v.z, v.w);
        }
        __syncthreads();

        f32x4 acc[4][4];
        #pragma unroll
        for (int rt = 0; rt < 4; ++rt)
            #pragma unroll
            for (int ct = 0; ct < 4; ++ct)
                acc[rt][ct] = (f32x4){ bv[ct], bv[ct], bv[ct], bv[ct] };

        #pragma unroll
        for (int rt = 0; rt < 4; ++rt) {
            bf16x8 a[4];
            int row = rt * 16 + ln15;
            #pragma unroll
            for (int kb = 0; kb < 4; ++kb) {
                int idx = (row * 128 + kb * 32 + g * 8) ^ ((row & 15) << 3);
                a[kb] = *(const bf16x8*)&hs[et][idx];
            }
            #pragma unroll
            for (int ct = 0; ct < 4; ++ct)
                #pragma unroll
                for (int kb = 0; kb < 4; ++kb)
                    acc[rt][ct] = __builtin_amdgcn_mfma_f32_16x16x32_bf16(
                        a[kb], fw[ct][kb], acc[rt][ct], 0, 0, 0);
        }

        #pragma unroll
        for (int rt = 0; rt < 4; ++rt)
            #pragma unroll
            for (int ct = 0; ct < 4; ++ct) {
                int col = colbase + ct * 16 + ln15;
                #pragma unroll
                for (int r = 0; r < 4; ++r) {
                    int row = base + et * 64 + rt * 16 + g * 4 + r;
                    if (row < nrows) {
                        float v = fmaxf(acc[rt][ct][r], 0.f) * scv[ct] + shv[ct];
                        out[(size_t)row * 128 + col] = v;
                    }
                }
            }
        __syncthreads();
    }
}

// -------------------------------------------------------------------------
// CSR aggregation (atomic-free): 32 lanes per node, 8 nodes per block.
// -------------------------------------------------------------------------
__global__ __launch_bounds__(256)
void agg_kernel(const unsigned short* __restrict__ emb,
                const float* __restrict__ x,
                const int* __restrict__ srcPerm,
                const int* __restrict__ offsets,
                float* __restrict__ agg,
                int c0, int c1, int first)
{
    const int slot = threadIdx.x >> 5;
    const int l    = threadIdx.x & 31;
    const int n = blockIdx.x * 8 + slot;
    if (n >= N_NODES_C) return;

    int lo = offsets[n], hi = offsets[n + 1];
    lo = max(lo, c0); hi = min(hi, c1);

    float4 s = make_float4(0.f, 0.f, 0.f, 0.f);
    const bool any = lo < hi;
    for (int pos = lo; pos < hi; ++pos) {
        int srcn = srcPerm[pos];
        ushort4 eb = *(const ushort4*)&emb[(size_t)(pos - c0) * DIM_C + l * 4];
        float4 xv = *(const float4*)&x[(size_t)srcn * DIM_C + l * 4];
        s.x += fmaxf(xv.x + bf2f(eb.x), 0.f);
        s.y += fmaxf(xv.y + bf2f(eb.y), 0.f);
        s.z += fmaxf(xv.z + bf2f(eb.z), 0.f);
        s.w += fmaxf(xv.w + bf2f(eb.w), 0.f);
    }

    float4* ap = (float4*)&agg[(size_t)n * DIM_C + l * 4];
    if (first) {
        *ap = s;
    } else if (any) {
        float4 o = *ap;
        o.x += s.x; o.y += s.y; o.z += s.z; o.w += s.w;
        *ap = o;
    }
}

// -------------------------------------------------------------------------
// Segmented mean pool: one block per graph, batch is sorted.
// -------------------------------------------------------------------------
__global__ __launch_bounds__(128)
void pool2_kernel(const float* __restrict__ x,
                  const int* __restrict__ goff,
                  float* __restrict__ pooled)
{
    const int g = blockIdx.x;
    const int tid = threadIdx.x;
    int lo = goff[g], hi = goff[g + 1];
    float s = 0.f;
    for (int n = lo; n < hi; ++n)
        s += x[(size_t)n * DIM_C + tid];
    float c = (float)max(hi - lo, 1);
    pooled[g * DIM_C + tid] = s / c;
}

// -------------------------------------------------------------------------
// Readout head
// -------------------------------------------------------------------------
__global__ __launch_bounds__(128)
void head_kernel(const float* __restrict__ pooled,
                 const float* __restrict__ l1w,
                 const float* __restrict__ l1b,
                 const float* __restrict__ l2w,
                 const float* __restrict__ l2b,
                 float* __restrict__ out)
{
    const int g = blockIdx.x;
    const int tid = threadIdx.x;
    __shared__ float ps[DIM_C];
    __shared__ float hsx[DIM_C];
    __shared__ float lg[N_CLASSES_C];
    __shared__ float lse;

    ps[tid] = pooled[g * DIM_C + tid];
    __syncthreads();

    float a = l1b[tid];
    for (int k = 0; k < DIM_C; ++k)
        a += ps[k] * l1w[k * DIM_C + tid];
    hsx[tid] = fmaxf(a, 0.f);
    __syncthreads();

    if (tid < N_CLASSES_C) {
        float s = l2b[tid];
        for (int f = 0; f < DIM_C; ++f)
            s += hsx[f] * l2w[f * N_CLASSES_C + tid];
        lg[tid] = s;
    }
    __syncthreads();

    if (tid == 0) {
        float m = lg[0];
        for (int cc = 1; cc < N_CLASSES_C; ++cc) m = fmaxf(m, lg[cc]);
        float s = 0.f;
        for (int cc = 0; cc < N_CLASSES_C; ++cc) s += expf(lg[cc] - m);
        lse = m + logf(s);
    }
    __syncthreads();

    if (tid < N_CLASSES_C)
        out[g * N_CLASSES_C + tid] = lg[tid] - lse;
}

// -------------------------------------------------------------------------
extern "C" void kernel_launch(void* const* d_in, const int* in_sizes, int n_in,
                              void* d_out, int out_size, void* d_ws, size_t ws_size,
                              hipStream_t stream)
{
    const float* x         = (const float*)d_in[0];
    const float* edge_attr = (const float*)d_in[1];
    const int*   ei        = (const int*)d_in[2];
    const int*   batch     = (const int*)d_in[3];
    const float* ee_w1     = (const float*)d_in[4];
    const float* ee_b1     = (const float*)d_in[5];
    const float* ee_w2     = (const float*)d_in[6];
    const float* ee_b2     = (const float*)d_in[7];
    const float* ee_bn_g   = (const float*)d_in[8];
    const float* ee_bn_b   = (const float*)d_in[9];
    const float* ee_bn_rm  = (const float*)d_in[10];
    const float* ee_bn_rv  = (const float*)d_in[11];
    const float* mlp_w1    = (const float*)d_in[12];
    const float* mlp_b1    = (const float*)d_in[13];
    const float* mlp_w2    = (const float*)d_in[14];
    const float* mlp_b2    = (const float*)d_in[15];
    const float* mlp_bn_g  = (const float*)d_in[16];
    const float* mlp_bn_b  = (const float*)d_in[17];
    const float* mlp_bn_rm = (const float*)d_in[18];
    const float* mlp_bn_rv = (const float*)d_in[19];
    const float* lin1_w    = (const float*)d_in[20];
    const float* lin1_b    = (const float*)d_in[21];
    const float* lin2_w    = (const float*)d_in[22];
    const float* lin2_b    = (const float*)d_in[23];
    float* out = (float*)d_out;

    const int* src = ei;
    const int* dst = ei + N_EDGES_C;

    // ---- workspace layout: fixed part first, emb buffer takes the rest ----
    char* wsp = (char*)d_ws;
    float* x_cur = (float*)wsp;          wsp += (size_t)N_NODES_C * DIM_C * 4;       // 25.6 MB
    float* agg   = (float*)wsp;          wsp += (size_t)N_NODES_C * DIM_C * 4;       // 25.6 MB
    unsigned short* eaPermH = (unsigned short*)wsp;
                                         wsp += (size_t)N_EDGES_C * EDGE_DIM_C * 2;  // 16 MB
    int* srcPerm = (int*)wsp;            wsp += (size_t)N_EDGES_C * 4;               // 2 MB
    int* cnt     = (int*)wsp;            wsp += 200704;
    int* offsets = (int*)wsp;            wsp += 200704;
    int* cursor  = (int*)wsp;            wsp += 200704;
    int* incl    = (int*)wsp;            wsp += 200704;
    int* bsum    = (int*)wsp;            wsp += 4096;
    int* goff    = (int*)wsp;            wsp += 4096;
    float* pooled = (float*)wsp;         wsp += (size_t)N_GRAPHS_C * DIM_C * 4;
    short* W1T   = (short*)wsp;          wsp += (size_t)N_LAYERS_C * 128 * 16 * 2;
    short* W2T   = (short*)wsp;          wsp += (size_t)N_LAYERS_C * 128 * 128 * 2;
    short* MT1   = (short*)wsp;          wsp += (size_t)N_LAYERS_C * 128 * 128 * 2;
    short* MT2   = (short*)wsp;          wsp += (size_t)N_LAYERS_C * 128 * 128 * 2;
    unsigned short* emb = (unsigned short*)wsp;   // rest of workspace

    // dynamic chunk: as many edge rows as fit (full 500k needs ~128 MB)
    size_t used = (size_t)(wsp - (char*)d_ws);
    size_t embRows = (ws_size > used) ? (ws_size - used) / ((size_t)DIM_C * 2) : 0;
    int chunk = (int)((embRows < (size_t)N_EDGES_C) ? embRows : (size_t)N_EDGES_C);
    if (chunk < 128) chunk = 128;  // minimal fallback (ws should never be this small)

    // ---- preprocess ----
    wprep_kernel<<<12, 256, 0, stream>>>(ee_w1, ee_w2, mlp_w1, mlp_w2,
                                         W1T, W2T, MT1, MT2);
    hipMemsetAsync(cnt, 0, N_NODES_C * sizeof(int), stream);
    hist_kernel<<<(N_EDGES_C + 255) / 256, 256, 0, stream>>>(dst, cnt);
    scan1_kernel<<<SCAN_NB, 1024, 0, stream>>>(cnt, incl, bsum);
    scan2_kernel<<<1, 64, 0, stream>>>(bsum);
    scan3_kernel<<<SCAN_NB, 1024, 0, stream>>>(cnt, incl, bsum, offsets, cursor);
    scatter_kernel<<<(N_EDGES_C + 255) / 256, 256, 0, stream>>>(
        src, dst, edge_attr, cursor, srcPerm, eaPermH);
    goff_kernel<<<1, 512, 0, stream>>>(batch, goff);

    const float* xin = x;
    for (int i = 0; i < N_LAYERS_C; ++i) {
        for (int c0 = 0; c0 < N_EDGES_C; c0 += chunk) {
            int c1 = min(c0 + chunk, N_EDGES_C);
            emb_mfma<<<256, 256, 0, stream>>>(
                eaPermH,
                W1T + (size_t)i * 128 * 16, ee_b1 + i * DIM_C,
                W2T + (size_t)i * 128 * 128, ee_b2 + i * DIM_C,
                ee_bn_g + i * DIM_C, ee_bn_b + i * DIM_C,
                ee_bn_rm + i * DIM_C, ee_bn_rv + i * DIM_C,
                emb, c0, c1 - c0);
            agg_kernel<<<(N_NODES_C + 7) / 8, 256, 0, stream>>>(
                emb, xin, srcPerm, offsets, agg, c0, c1, c0 == 0 ? 1 : 0);
        }
        node_mfma<<<256, 256, 0, stream>>>(
            xin, agg,
            MT1 + (size_t)i * 128 * 128, mlp_b1 + i * DIM_C,
            mlp_bn_g + i * DIM_C, mlp_bn_b + i * DIM_C,
            mlp_bn_rm + i * DIM_C, mlp_bn_rv + i * DIM_C,
            agg, N_NODES_C, 0);
        node_mfma<<<256, 256, 0, stream>>>(
            agg, nullptr,
            MT2 + (size_t)i * 128 * 128, mlp_b2 + i * DIM_C,
            mlp_bn_g + i * DIM_C, mlp_bn_b + i * DIM_C,
            mlp_bn_rm + i * DIM_C, mlp_bn_rv + i * DIM_C,
            x_cur, N_NODES_C, 1);
        xin = x_cur;
    }

    pool2_kernel<<<N_GRAPHS_C, 128, 0, stream>>>(xin, goff, pooled);
    head_kernel<<<N_GRAPHS_C, 128, 0, stream>>>(pooled, lin1_w, lin1_b,
                                                lin2_w, lin2_b, out);
}